// Round 12
// baseline (275.995 us; speedup 1.0000x reference)
//
#include <hip/hip_runtime.h>
#include <cmath>

#define H 96
#define W 96
#define HW 9216
#define CIN 256
#define COUT 256
#define NB 4
#define NCH 72   // K-chunks of 32 kc
#define NGR 36   // K-groups of 64 kc: g = c2*9 + k (c2-OUTER, k-inner: L1-friendly)
#define NIV 18   // offset_gemm: intervals of 2 groups (BK=128)
#define FNIV 12  // fused_gemm: intervals of 3 groups (BK=192): 13 barriers vs 19
#define TPX 48   // fused_gemm pixel tile: 192 tiles x 4 n = 768 blocks = 3/CU EXACTLY

typedef float f32x4 __attribute__((ext_vector_type(4)));
typedef float f32x2 __attribute__((ext_vector_type(2)));
typedef short bf16x8 __attribute__((ext_vector_type(8)));

__device__ __forceinline__ unsigned short f2bf(float f) {
  unsigned int u = __float_as_uint(f);
  u += 0x7fff + ((u >> 16) & 1);  // round-to-nearest-even
  return (unsigned short)(u >> 16);
}
__device__ __forceinline__ float bf2f(unsigned short u) {
  return __uint_as_float(((unsigned int)u) << 16);
}
__device__ __forceinline__ f32x2 up2(unsigned int u) {
  f32x2 r;
  r.x = __uint_as_float(u << 16);
  r.y = __uint_as_float(u & 0xffff0000u);
  return r;
}
// one-instr RNE pack of two f32 -> packed bf16x2
__device__ __forceinline__ unsigned int cvtpk(float lo, float hi) {
  unsigned int r;
  asm("v_cvt_pk_bf16_f32 %0, %1, %2" : "=v"(r) : "v"(lo), "v"(hi));
  return r;
}

// Raw barrier with LDS-only drain (keeps global loads in flight).
__device__ __forceinline__ void bar() {
  asm volatile("s_waitcnt lgkmcnt(0)" ::: "memory");
  __builtin_amdgcn_s_barrier();
  asm volatile("" ::: "memory");
}

// ---------------------------------------------------------------------------
// Kernel P: PREP = xt_convert (blocks 0..2303) + wa_all (blocks 2304..2628).
// ---------------------------------------------------------------------------
__global__ __launch_bounds__(256)
void prep(const float* __restrict__ x, unsigned short* __restrict__ xT,
          const float* __restrict__ w, const float* __restrict__ w_off,
          unsigned short* __restrict__ Ag, unsigned short* __restrict__ Ag2,
          float* __restrict__ sumArr) {
  __shared__ unsigned short ls[64][72];
  int bx = blockIdx.x;
  int tid = threadIdx.x;

  if (bx < 2304) {
    // ---- xt_convert: bx = n*576 + cb*144 + hwt
    int n   = bx / 576;
    int rem = bx - n * 576;
    int cb  = rem / 144;
    int hwt = rem - cb * 144;
    int hwbase = hwt * 64;
    int cbase  = cb * 64;
    {
      int cl = tid >> 2, qd = tid & 3;
      const float* src = x + ((size_t)(n * CIN + cbase + cl)) * HW + hwbase + qd * 16;
#pragma unroll
      for (int m = 0; m < 4; ++m) {
        float4 v = *(const float4*)(src + m * 4);
        int hwl = qd * 16 + m * 4;
        ls[hwl + 0][cl] = f2bf(v.x);
        ls[hwl + 1][cl] = f2bf(v.y);
        ls[hwl + 2][cl] = f2bf(v.z);
        ls[hwl + 3][cl] = f2bf(v.w);
      }
    }
    __syncthreads();
    {
      int hw = tid >> 2, part = tid & 3;
      unsigned short* dst = xT + ((size_t)(n * HW + hwbase + hw)) * CIN + cbase + part * 16;
      *(uint4*)(dst + 0) = *(const uint4*)(&ls[hw][part * 16 + 0]);
      *(uint4*)(dst + 8) = *(const uint4*)(&ls[hw][part * 16 + 8]);
    }
  } else if (bx < 2592) {    // ---- main weights: 288 blocks
    int gid = (bx - 2304) * 256 + tid;
    int ch = gid >> 10;
    int rest = gid & 1023;
    int ot = rest >> 6, l = rest & 63;
    int o = ot * 16 + (l & 15);
    int k = ch >> 3, cc = ch & 7;
    int cbase = cc * 32 + (l >> 4) * 8;
    unsigned short r[8];
#pragma unroll
    for (int j = 0; j < 8; ++j)
      r[j] = f2bf(w[((size_t)o * CIN + cbase + j) * 9 + k]);
    uint4 pk;
    pk.x = (unsigned int)r[0] | ((unsigned int)r[1] << 16);
    pk.y = (unsigned int)r[2] | ((unsigned int)r[3] << 16);
    pk.z = (unsigned int)r[4] | ((unsigned int)r[5] << 16);
    pk.w = (unsigned int)r[6] | ((unsigned int)r[7] << 16);
    *(uint4*)(Ag + (size_t)gid * 8) = pk;
  } else if (bx < 2628) {    // ---- offset weights: 36 blocks
    int gid = (bx - 2592) * 256 + tid;
    int ch = gid >> 7;
    int rest = gid & 127;
    int ot = rest >> 6, l = rest & 63;
    int o = ot * 16 + (l & 15);
    int k = ch >> 3, cc = ch & 7;
    int cbase = cc * 32 + (l >> 4) * 8;
    unsigned short r[8];
#pragma unroll
    for (int j = 0; j < 8; ++j)
      r[j] = (o < 27) ? f2bf(w_off[((size_t)o * CIN + cbase + j) * 9 + k]) : (unsigned short)0;
    uint4 pk;
    pk.x = (unsigned int)r[0] | ((unsigned int)r[1] << 16);
    pk.y = (unsigned int)r[2] | ((unsigned int)r[3] << 16);
    pk.z = (unsigned int)r[4] | ((unsigned int)r[5] << 16);
    pk.w = (unsigned int)r[6] | ((unsigned int)r[7] << 16);
    *(uint4*)(Ag2 + (size_t)gid * 8) = pk;
  } else {                   // ---- zero sumArr[256] + sqArr[256] (contiguous)
    sumArr[tid] = 0.f;
    sumArr[256 + tid] = 0.f;
  }
}

// ---------------------------------------------------------------------------
// Kernel O: offset conv bf16 MFMA GEMM, BK=128 intervals, depth-2 prefetch.
// 256 threads, 64-px tiles; short (~23us). Unchanged.
// ---------------------------------------------------------------------------
__global__ __launch_bounds__(256, 4)
void offset_gemm(const unsigned short* __restrict__ xT,
                 const unsigned short* __restrict__ Ag2,
                 const float* __restrict__ b_off,
                 float* __restrict__ py, float* __restrict__ px,
                 float* __restrict__ mk) {
  __shared__ int sPos[9][64];
  __shared__ unsigned short sB[2][2][4096];  // [bufpair][group-half][64px*64kc]

  int tid = threadIdx.x;
  int wv = tid >> 6, lane = tid & 63, quad = lane >> 4, l16 = lane & 15;
  int pixBase = blockIdx.x * 64;
  int n = blockIdx.y;
  const unsigned short* xTn = xT + (size_t)n * HW * CIN;

  if (tid < 64) {
    int hwp = pixBase + tid;
    int hh = hwp / W, wx = hwp % W;
#pragma unroll
    for (int ty = 0; ty < 3; ++ty) {
#pragma unroll
      for (int tx = 0; tx < 3; ++tx) {
        int iy = hh + ty - 1, ix = wx + tx - 1;
        bool ok = (iy >= 0) && (iy < H) && (ix >= 0) && (ix < W);
        sPos[ty * 3 + tx][tid] = ok ? (iy * W + ix) : -1;
      }
    }
  }
  bar();

  int pix0 = tid >> 3, ck0 = tid & 7;
  int pix1 = 32 + (tid >> 3);
  int a0 = (ck0 >> 2) * 2048 + (pix0 >> 4) * 512 + ((ck0 & 3) * 16 + ((pix0 & 15) ^ (ck0 & 3))) * 8;
  int a1 = (ck0 >> 2) * 2048 + (pix1 >> 4) * 512 + ((ck0 & 3) * 16 + ((pix1 & 15) ^ (ck0 & 3))) * 8;

  f32x4 acc[2];
  acc[0] = (f32x4){0.f, 0.f, 0.f, 0.f};
  acc[1] = (f32x4){0.f, 0.f, 0.f, 0.f};

  uint4 dA[2], dB[2];
  auto issue = [&](int g, uint4* d) {
    int k = g % 9, c2 = g / 9;
    int p0 = sPos[k][pix0], p1 = sPos[k][pix1];
    d[0] = (uint4){0, 0, 0, 0};
    d[1] = (uint4){0, 0, 0, 0};
    if (p0 >= 0) d[0] = *(const uint4*)(xTn + (size_t)p0 * CIN + c2 * 64 + ck0 * 8);
    if (p1 >= 0) d[1] = *(const uint4*)(xTn + (size_t)p1 * CIN + c2 * 64 + ck0 * 8);
  };

  bf16x8 afr[4];
  auto aload = [&](int g) {
    int k = g % 9, c2 = g / 9;
    int ch = k * 8 + c2 * 2;
#pragma unroll
    for (int s = 0; s < 2; ++s)
#pragma unroll
      for (int ot = 0; ot < 2; ++ot)
        afr[s * 2 + ot] = *(const bf16x8*)(Ag2 + ((size_t)((ch + s) * 2 + ot) * 64 + lane) * 8);
  };

  int rdAddr0 = wv * 512 + (quad * 16 + (l16 ^ quad)) * 8;
  auto mfmaPhase = [&](int buf, int half) {
    const unsigned short* base = &sB[buf][half][0];
    __builtin_amdgcn_s_setprio(1);
#pragma unroll
    for (int s = 0; s < 2; ++s) {
      bf16x8 bfr = *(const bf16x8*)(base + s * 2048 + rdAddr0);
      acc[0] = __builtin_amdgcn_mfma_f32_16x16x32_bf16(afr[s * 2 + 0], bfr, acc[0], 0, 0, 0);
      acc[1] = __builtin_amdgcn_mfma_f32_16x16x32_bf16(afr[s * 2 + 1], bfr, acc[1], 0, 0, 0);
    }
    __builtin_amdgcn_s_setprio(0);
  };
  auto store = [&](uint4* d, int buf, int half) {
    *(uint4*)(&sB[buf][half][a0]) = d[0];
    *(uint4*)(&sB[buf][half][a1]) = d[1];
  };

  // prologue: stage g0,g1 into buf0; g2,g3 corners in flight
  issue(0, dA);
  issue(1, dB);
  aload(0);
  store(dA, 0, 0);
  issue(2, dA);
  store(dB, 0, 1);
  issue(3, dB);
  bar();

  for (int i = 0; i < NIV; ++i) {
    int buf = i & 1;
    mfmaPhase(buf, 0);                   // group 2i
    aload(2 * i + 1);
    if (i < NIV - 1) store(dA, buf ^ 1, 0);      // group 2i+2
    if (i < NIV - 2) issue(2 * i + 4, dA);
    mfmaPhase(buf, 1);                   // group 2i+1
    if (i < NIV - 1) store(dB, buf ^ 1, 1);      // group 2i+3
    if (i < NIV - 2) issue(2 * i + 5, dB);
    if (i < NIV - 1) aload(2 * i + 2);
    bar();
  }

  // Epilogue
  int pix = pixBase + wv * 16 + l16;
  int he = pix / W, we = pix % W;
#pragma unroll
  for (int ot = 0; ot < 2; ++ot) {
#pragma unroll
    for (int r = 0; r < 4; ++r) {
      int kk = ot * 16 + quad * 4 + r;
      if (kk >= 27) continue;
      float v = acc[ot][r] + b_off[kk];
      if (kk < 9) {
        py[(size_t)(n * 9 + kk) * HW + pix] = v + (float)he + (float)(kk / 3 - 1);
      } else if (kk < 18) {
        int j = kk - 9;
        px[(size_t)(n * 9 + j) * HW + pix] = v + (float)we + (float)(j % 3 - 1);
      } else {
        mk[(size_t)(n * 9 + (kk - 18)) * HW + pix] = 1.f / (1.f + expf(-v));
      }
    }
  }
}

// ---------------------------------------------------------------------------
// Kernel G: FUSED bilinear-sample + bf16 MFMA GEMM, 48-px tiles, BK=192
// intervals (3 groups per barrier: 13 barriers vs 19 -- the proven lever
// from r5, latency-chain bound per r10). LDS = 6912+6912+36864 = 50688B ->
// EXACTLY 3 blocks/CU (>40960 so no 4th block); grid 768 = capacity ->
// one balanced dispatch wave. 6 waves stage; all 8 MFMA.
// Register floor ~110-130 total -> never request >4 waves/EU (round 8:
// (512,8) => 64-reg budget => 2.8GB scratch spill, 780us).
// ---------------------------------------------------------------------------
__global__ __launch_bounds__(512, 4)
void fused_gemm(const unsigned short* __restrict__ xT,
                const unsigned short* __restrict__ Ag,
                const float* __restrict__ py,
                const float* __restrict__ px,
                const float* __restrict__ mk,
                unsigned short* __restrict__ yb,
                float* __restrict__ sumArr, float* __restrict__ sqArr) {
  __shared__ int   sIdx4[9][TPX][4];           // 6912 B
  __shared__ float sWgt4[9][TPX][4];           // 6912 B
  __shared__ unsigned short sB[2][3][3072];    // 36864 B: [bufpair][half0..2][48px*64kc]

  int tid = threadIdx.x;
  int wv = tid >> 6, lane = tid & 63, quad = lane >> 4, l16 = lane & 15;
  int pixBase = blockIdx.x * TPX;
  int n = blockIdx.y;
  const unsigned short* xTn = xT + (size_t)n * HW * CIN;

  // ---- prologue: corner indices + mask-folded weights, 48 px x 9 taps
  if (tid < 9 * TPX) {
    int k = tid / TPX, pix0 = tid - k * TPX;
    int off = (n * 9 + k) * HW + pixBase + pix0;
    float fy = py[off], fx = px[off], fm = mk[off];
    float y0f = floorf(fy), x0f = floorf(fx);
    float ly = fy - y0f, lx = fx - x0f;
    int y0 = (int)y0f, x0 = (int)x0f;
    int cy0 = min(max(y0, 0), H - 1), cy1 = min(max(y0 + 1, 0), H - 1);
    int cx0 = min(max(x0, 0), W - 1), cx1 = min(max(x0 + 1, 0), W - 1);
    float vy0 = (y0 >= 0 && y0 <= H - 1) ? 1.f : 0.f;
    float vy1 = (y0 + 1 >= 0 && y0 + 1 <= H - 1) ? 1.f : 0.f;
    float vx0 = (x0 >= 0 && x0 <= W - 1) ? 1.f : 0.f;
    float vx1 = (x0 + 1 >= 0 && x0 + 1 <= W - 1) ? 1.f : 0.f;
    int4 iv;
    iv.x = cy0 * W + cx0;
    iv.y = cy0 * W + cx1;
    iv.z = cy1 * W + cx0;
    iv.w = cy1 * W + cx1;
    float4 wf;
    wf.x = (1.f - ly) * (1.f - lx) * fm * vy0 * vx0;
    wf.y = (1.f - ly) * lx * fm * vy0 * vx1;
    wf.z = ly * (1.f - lx) * fm * vy1 * vx0;
    wf.w = ly * lx * fm * vy1 * vx1;
    *(int4*)(&sIdx4[k][pix0][0]) = iv;
    *(float4*)(&sWgt4[k][pix0][0]) = wf;
  }
  bar();

  // sampler role: waves 0-5; 4 consecutive lanes = 1 corner-row line
  int wvm3 = wv % 3, wvd3 = wv / 3;           // pt-tile, chunk-half (wv<6)
  bool samp = (wv < 6);
  int pixS  = (wvm3 << 4) | (lane >> 2);      // 0..47
  int qS    = lane & 3;
  int chunk = (wvd3 << 2) | qS;               // 0..7
  int co    = chunk * 8;
  int sAddr = (chunk >> 2) * 1536 + wvm3 * 512 + (qS * 16 + ((lane >> 2) ^ qS)) * 8;

  f32x4 acc[2][3];
#pragma unroll
  for (int i = 0; i < 2; ++i)
#pragma unroll
    for (int pt = 0; pt < 3; ++pt) acc[i][pt] = (f32x4){0.f, 0.f, 0.f, 0.f};

  uint4 cnA[4], cnB[4], cnC[4];
  float wgA[4], wgB[4], wgC[4];
  auto issue = [&](int g, uint4* cn, float* wt) {
    int k = g % 9, c2 = g / 9;
    int4 iv = *(const int4*)(&sIdx4[k][pixS][0]);
    float4 wf = *(const float4*)(&sWgt4[k][pixS][0]);
    int coff = c2 * 64 + co;
    cn[0] = *(const uint4*)(xTn + (size_t)iv.x * CIN + coff);
    cn[1] = *(const uint4*)(xTn + (size_t)iv.y * CIN + coff);
    cn[2] = *(const uint4*)(xTn + (size_t)iv.z * CIN + coff);
    cn[3] = *(const uint4*)(xTn + (size_t)iv.w * CIN + coff);
    wt[0] = wf.x; wt[1] = wf.y; wt[2] = wf.z; wt[3] = wf.w;
  };

  auto blendOne = [&](unsigned int u0, unsigned int u1, unsigned int u2,
                      unsigned int u3, const float* wt) -> unsigned int {
    f32x2 s = up2(u0) * wt[0];       // v_pk_fma chain
    s += up2(u1) * wt[1];
    s += up2(u2) * wt[2];
    s += up2(u3) * wt[3];
    return cvtpk(s.x, s.y);          // 1-instr RNE pack
  };
  auto blendStore = [&](uint4* cn, const float* wt, int buf, int half) {
    uint4 r;
    r.x = blendOne(cn[0].x, cn[1].x, cn[2].x, cn[3].x, wt);
    r.y = blendOne(cn[0].y, cn[1].y, cn[2].y, cn[3].y, wt);
    r.z = blendOne(cn[0].z, cn[1].z, cn[2].z, cn[3].z, wt);
    r.w = blendOne(cn[0].w, cn[1].w, cn[2].w, cn[3].w, wt);
    *(uint4*)(&sB[buf][half][sAddr]) = r;
  };

  bf16x8 afr[4];
  auto aload = [&](int g) {
    int k = g % 9, c2 = g / 9;
    int ch = k * 8 + c2 * 2;
#pragma unroll
    for (int s = 0; s < 2; ++s)
#pragma unroll
      for (int ot = 0; ot < 2; ++ot)
        afr[s * 2 + ot] = *(const bf16x8*)(Ag + ((size_t)((ch + s) * 16 + 2 * wv + ot) * 64 + lane) * 8);
  };

  int rdBase = (quad * 16 + (l16 ^ quad)) * 8;
  auto mfmaPhase = [&](int buf, int half) {
    const unsigned short* base = &sB[buf][half][0];
    __builtin_amdgcn_s_setprio(1);
#pragma unroll
    for (int s = 0; s < 2; ++s) {
      bf16x8 bfr[3];
#pragma unroll
      for (int pt = 0; pt < 3; ++pt)
        bfr[pt] = *(const bf16x8*)(base + s * 1536 + pt * 512 + rdBase);
#pragma unroll
      for (int pt = 0; pt < 3; ++pt) {
        acc[0][pt] = __builtin_amdgcn_mfma_f32_16x16x32_bf16(afr[s * 2 + 0], bfr[pt], acc[0][pt], 0, 0, 0);
        acc[1][pt] = __builtin_amdgcn_mfma_f32_16x16x32_bf16(afr[s * 2 + 1], bfr[pt], acc[1][pt], 0, 0, 0);
      }
    }
    __builtin_amdgcn_s_setprio(0);
  };

  // prologue: blend g0..g2 into buf0; g3..g5 corner loads in flight across bar
  if (samp) {
    issue(0, cnA, wgA);
    issue(1, cnB, wgB);
    issue(2, cnC, wgC);
  }
  aload(0);
  if (samp) {
    blendStore(cnA, wgA, 0, 0);
    blendStore(cnB, wgB, 0, 1);
    blendStore(cnC, wgC, 0, 2);
    issue(3, cnA, wgA);
    issue(4, cnB, wgB);
    issue(5, cnC, wgC);
  }
  bar();

  for (int i = 0; i < FNIV; ++i) {
    int buf = i & 1;
    mfmaPhase(buf, 0);                        // group 3i
    aload(3 * i + 1);
    if (samp && i < FNIV - 1) blendStore(cnA, wgA, buf ^ 1, 0);   // group 3i+3
    if (samp && i < FNIV - 2) issue(3 * i + 6, cnA, wgA);
    mfmaPhase(buf, 1);                        // group 3i+1
    aload(3 * i + 2);
    if (samp && i < FNIV - 1) blendStore(cnB, wgB, buf ^ 1, 1);   // group 3i+4
    if (samp && i < FNIV - 2) issue(3 * i + 7, cnB, wgB);
    mfmaPhase(buf, 2);                        // group 3i+2
    if (samp && i < FNIV - 1) blendStore(cnC, wgC, buf ^ 1, 2);   // group 3i+5
    if (samp && i < FNIV - 2) issue(3 * i + 8, cnC, wgC);
    if (i < FNIV - 1) aload(3 * i + 3);
    bar();
  }

  // Epilogue: D col = l16 (pix), row = quad*4 + r (o within 16-tile)
#pragma unroll
  for (int ot = 0; ot < 2; ++ot) {
#pragma unroll
    for (int r = 0; r < 4; ++r) {
      int o = (2 * wv + ot) * 16 + quad * 4 + r;
      unsigned short* rowp = yb + (size_t)(n * COUT + o) * HW + pixBase;
      float s = 0.f, q = 0.f;
#pragma unroll
      for (int pt = 0; pt < 3; ++pt) {
        float v = acc[ot][pt][r];
        rowp[pt * 16 + l16] = f2bf(v);
        s += v;
        q = fmaf(v, v, q);
      }
#pragma unroll
      for (int m = 8; m >= 1; m >>= 1) {
        s += __shfl_xor(s, m, 64);
        q += __shfl_xor(q, m, 64);
      }
      if (l16 == 0) {
        atomicAdd(&sumArr[o], s);
        atomicAdd(&sqArr[o], q);
      }
    }
  }
}

// ---------------------------------------------------------------------------
// BN apply with inlined finalize (bf16 y -> fp32 out).
// ---------------------------------------------------------------------------
__global__ __launch_bounds__(256)
void bn_apply(const unsigned short* __restrict__ yb,
              float* __restrict__ out,
              const float* __restrict__ sumArr,
              const float* __restrict__ sqArr,
              const float* __restrict__ gamma,
              const float* __restrict__ beta) {
  int gid = blockIdx.x * 256 + threadIdx.x;  // < NB*COUT*HW/8
  int base = gid * 8;
  int o = (base / HW) % COUT;
  const float inv = 1.f / (float)(NB * HW);
  float mean = sumArr[o] * inv;
  float var = sqArr[o] * inv - mean * mean;
  float scale = rsqrtf(var + 1e-5f) * gamma[o];
  float shift = beta[o] - mean * scale;
  uint4 v = ((const uint4*)yb)[gid];
  float4 a, b;
  a.x = fmaxf(fmaf(bf2f((unsigned short)(v.x & 0xffff)), scale, shift), 0.f);
  a.y = fmaxf(fmaf(bf2f((unsigned short)(v.x >> 16)), scale, shift), 0.f);
  a.z = fmaxf(fmaf(bf2f((unsigned short)(v.y & 0xffff)), scale, shift), 0.f);
  a.w = fmaxf(fmaf(bf2f((unsigned short)(v.y >> 16)), scale, shift), 0.f);
  b.x = fmaxf(fmaf(bf2f((unsigned short)(v.z & 0xffff)), scale, shift), 0.f);
  b.y = fmaxf(fmaf(bf2f((unsigned short)(v.z >> 16)), scale, shift), 0.f);
  b.z = fmaxf(fmaf(bf2f((unsigned short)(v.w & 0xffff)), scale, shift), 0.f);
  b.w = fmaxf(fmaf(bf2f((unsigned short)(v.w >> 16)), scale, shift), 0.f);
  *(float4*)&out[base] = a;
  *(float4*)&out[base + 4] = b;
}

// ---------------------------------------------------------------------------
extern "C" void kernel_launch(void* const* d_in, const int* in_sizes, int n_in,
                              void* d_out, int out_size, void* d_ws, size_t ws_size,
                              hipStream_t stream) {
  const float* x     = (const float*)d_in[0];
  const float* w_off = (const float*)d_in[1];
  const float* b_off = (const float*)d_in[2];
  const float* w     = (const float*)d_in[3];
  // d_in[4] = b : cancels exactly in BN mean-subtraction
  const float* gamma = (const float*)d_in[5];
  const float* beta  = (const float*)d_in[6];
  float* out = (float*)d_out;

  float* ws = (float*)d_ws;
  float* py = ws;                          // 331776 f
  float* px = py + 331776;
  float* mk = px + 331776;
  unsigned short* Ag  = (unsigned short*)(mk + 331776);  // 589824 u16
  unsigned short* Ag2 = Ag + 589824;                     // 73728 u16
  float* sumArr   = (float*)(Ag2 + 73728);
  float* sqArr    = sumArr + 256;                        // contiguous after sumArr
  unsigned short* yb = (unsigned short*)(sqArr + 256);   // 9437184 u16
  unsigned short* xT = yb + 9437184;                     // 9437184 u16

  prep<<<2629, 256, 0, stream>>>(x, xT, w, w_off, Ag, Ag2, sumArr);

  dim3 gO(HW / 64, NB);
  offset_gemm<<<gO, 256, 0, stream>>>(xT, Ag2, b_off, py, px, mk);

  dim3 gG(HW / TPX, NB);
  fused_gemm<<<gG, 512, 0, stream>>>(xT, Ag, py, px, mk, yb, sumArr, sqArr);

  bn_apply<<<(NB * COUT * HW / 8) / 256, 256, 0, stream>>>(yb, out, sumArr, sqArr, gamma, beta);
}

// Round 14
// 254.015 us; speedup vs baseline: 1.0865x; 1.0865x over previous
//
#include <hip/hip_runtime.h>
#include <cmath>

#define H 96
#define W 96
#define HW 9216
#define CIN 256
#define COUT 256
#define NB 4
#define NCH 72   // K-chunks of 32 kc
#define NGR 36   // K-groups of 64 kc: g = c2*9 + k (c2-OUTER, k-inner: L1-friendly)
#define NIV 18   // intervals of 2 groups (BK=128): one barrier each
#define TPX 48   // fused_gemm pixel tile: 192 tiles x 4 n = 768 blocks = 3/CU EXACTLY

// NOTE (r13): hipLaunchCooperativeKernel silently failed in this harness
// (output never written; absmax == max|ref|). Do NOT use grid.sync() here.
// NOTE (r12): BK=192 spilled (3rd corner-buffer set; WRITE 24.6->67MB) — BK=128 is the register ceiling.
// NOTE (r8): never request >4 waves/EU via launch_bounds — 64-reg budget => 2.8GB scratch, 780us.

typedef float f32x4 __attribute__((ext_vector_type(4)));
typedef float f32x2 __attribute__((ext_vector_type(2)));
typedef short bf16x8 __attribute__((ext_vector_type(8)));

__device__ __forceinline__ unsigned short f2bf(float f) {
  unsigned int u = __float_as_uint(f);
  u += 0x7fff + ((u >> 16) & 1);  // round-to-nearest-even
  return (unsigned short)(u >> 16);
}
__device__ __forceinline__ float bf2f(unsigned short u) {
  return __uint_as_float(((unsigned int)u) << 16);
}
__device__ __forceinline__ f32x2 up2(unsigned int u) {
  f32x2 r;
  r.x = __uint_as_float(u << 16);
  r.y = __uint_as_float(u & 0xffff0000u);
  return r;
}
// one-instr RNE pack of two f32 -> packed bf16x2
__device__ __forceinline__ unsigned int cvtpk(float lo, float hi) {
  unsigned int r;
  asm("v_cvt_pk_bf16_f32 %0, %1, %2" : "=v"(r) : "v"(lo), "v"(hi));
  return r;
}

// Raw barrier with LDS-only drain (keeps global loads in flight).
__device__ __forceinline__ void bar() {
  asm volatile("s_waitcnt lgkmcnt(0)" ::: "memory");
  __builtin_amdgcn_s_barrier();
  asm volatile("" ::: "memory");
}

// ---------------------------------------------------------------------------
// Kernel P: PREP = xt_convert (blocks 0..2303) + wa_all (blocks 2304..2628).
// ---------------------------------------------------------------------------
__global__ __launch_bounds__(256)
void prep(const float* __restrict__ x, unsigned short* __restrict__ xT,
          const float* __restrict__ w, const float* __restrict__ w_off,
          unsigned short* __restrict__ Ag, unsigned short* __restrict__ Ag2,
          float* __restrict__ sumArr) {
  __shared__ unsigned short ls[64][72];
  int bx = blockIdx.x;
  int tid = threadIdx.x;

  if (bx < 2304) {
    // ---- xt_convert: bx = n*576 + cb*144 + hwt
    int n   = bx / 576;
    int rem = bx - n * 576;
    int cb  = rem / 144;
    int hwt = rem - cb * 144;
    int hwbase = hwt * 64;
    int cbase  = cb * 64;
    {
      int cl = tid >> 2, qd = tid & 3;
      const float* src = x + ((size_t)(n * CIN + cbase + cl)) * HW + hwbase + qd * 16;
#pragma unroll
      for (int m = 0; m < 4; ++m) {
        float4 v = *(const float4*)(src + m * 4);
        int hwl = qd * 16 + m * 4;
        ls[hwl + 0][cl] = f2bf(v.x);
        ls[hwl + 1][cl] = f2bf(v.y);
        ls[hwl + 2][cl] = f2bf(v.z);
        ls[hwl + 3][cl] = f2bf(v.w);
      }
    }
    __syncthreads();
    {
      int hw = tid >> 2, part = tid & 3;
      unsigned short* dst = xT + ((size_t)(n * HW + hwbase + hw)) * CIN + cbase + part * 16;
      *(uint4*)(dst + 0) = *(const uint4*)(&ls[hw][part * 16 + 0]);
      *(uint4*)(dst + 8) = *(const uint4*)(&ls[hw][part * 16 + 8]);
    }
  } else if (bx < 2592) {    // ---- main weights: 288 blocks
    int gid = (bx - 2304) * 256 + tid;
    int ch = gid >> 10;
    int rest = gid & 1023;
    int ot = rest >> 6, l = rest & 63;
    int o = ot * 16 + (l & 15);
    int k = ch >> 3, cc = ch & 7;
    int cbase = cc * 32 + (l >> 4) * 8;
    unsigned short r[8];
#pragma unroll
    for (int j = 0; j < 8; ++j)
      r[j] = f2bf(w[((size_t)o * CIN + cbase + j) * 9 + k]);
    uint4 pk;
    pk.x = (unsigned int)r[0] | ((unsigned int)r[1] << 16);
    pk.y = (unsigned int)r[2] | ((unsigned int)r[3] << 16);
    pk.z = (unsigned int)r[4] | ((unsigned int)r[5] << 16);
    pk.w = (unsigned int)r[6] | ((unsigned int)r[7] << 16);
    *(uint4*)(Ag + (size_t)gid * 8) = pk;
  } else if (bx < 2628) {    // ---- offset weights: 36 blocks
    int gid = (bx - 2592) * 256 + tid;
    int ch = gid >> 7;
    int rest = gid & 127;
    int ot = rest >> 6, l = rest & 63;
    int o = ot * 16 + (l & 15);
    int k = ch >> 3, cc = ch & 7;
    int cbase = cc * 32 + (l >> 4) * 8;
    unsigned short r[8];
#pragma unroll
    for (int j = 0; j < 8; ++j)
      r[j] = (o < 27) ? f2bf(w_off[((size_t)o * CIN + cbase + j) * 9 + k]) : (unsigned short)0;
    uint4 pk;
    pk.x = (unsigned int)r[0] | ((unsigned int)r[1] << 16);
    pk.y = (unsigned int)r[2] | ((unsigned int)r[3] << 16);
    pk.z = (unsigned int)r[4] | ((unsigned int)r[5] << 16);
    pk.w = (unsigned int)r[6] | ((unsigned int)r[7] << 16);
    *(uint4*)(Ag2 + (size_t)gid * 8) = pk;
  } else {                   // ---- zero sumArr[256] + sqArr[256] (contiguous)
    sumArr[tid] = 0.f;
    sumArr[256 + tid] = 0.f;
  }
}

// ---------------------------------------------------------------------------
// Kernel O: offset conv bf16 MFMA GEMM, BK=128 intervals, depth-2 prefetch.
// 256 threads, 64-px tiles; short (~23us).
// ---------------------------------------------------------------------------
__global__ __launch_bounds__(256, 4)
void offset_gemm(const unsigned short* __restrict__ xT,
                 const unsigned short* __restrict__ Ag2,
                 const float* __restrict__ b_off,
                 float* __restrict__ py, float* __restrict__ px,
                 float* __restrict__ mk) {
  __shared__ int sPos[9][64];
  __shared__ unsigned short sB[2][2][4096];  // [bufpair][group-half][64px*64kc]

  int tid = threadIdx.x;
  int wv = tid >> 6, lane = tid & 63, quad = lane >> 4, l16 = lane & 15;
  int pixBase = blockIdx.x * 64;
  int n = blockIdx.y;
  const unsigned short* xTn = xT + (size_t)n * HW * CIN;

  if (tid < 64) {
    int hwp = pixBase + tid;
    int hh = hwp / W, wx = hwp % W;
#pragma unroll
    for (int ty = 0; ty < 3; ++ty) {
#pragma unroll
      for (int tx = 0; tx < 3; ++tx) {
        int iy = hh + ty - 1, ix = wx + tx - 1;
        bool ok = (iy >= 0) && (iy < H) && (ix >= 0) && (ix < W);
        sPos[ty * 3 + tx][tid] = ok ? (iy * W + ix) : -1;
      }
    }
  }
  bar();

  int pix0 = tid >> 3, ck0 = tid & 7;
  int pix1 = 32 + (tid >> 3);
  int a0 = (ck0 >> 2) * 2048 + (pix0 >> 4) * 512 + ((ck0 & 3) * 16 + ((pix0 & 15) ^ (ck0 & 3))) * 8;
  int a1 = (ck0 >> 2) * 2048 + (pix1 >> 4) * 512 + ((ck0 & 3) * 16 + ((pix1 & 15) ^ (ck0 & 3))) * 8;

  f32x4 acc[2];
  acc[0] = (f32x4){0.f, 0.f, 0.f, 0.f};
  acc[1] = (f32x4){0.f, 0.f, 0.f, 0.f};

  uint4 dA[2], dB[2];
  auto issue = [&](int g, uint4* d) {
    int k = g % 9, c2 = g / 9;
    int p0 = sPos[k][pix0], p1 = sPos[k][pix1];
    d[0] = (uint4){0, 0, 0, 0};
    d[1] = (uint4){0, 0, 0, 0};
    if (p0 >= 0) d[0] = *(const uint4*)(xTn + (size_t)p0 * CIN + c2 * 64 + ck0 * 8);
    if (p1 >= 0) d[1] = *(const uint4*)(xTn + (size_t)p1 * CIN + c2 * 64 + ck0 * 8);
  };

  bf16x8 afr[4];
  auto aload = [&](int g) {
    int k = g % 9, c2 = g / 9;
    int ch = k * 8 + c2 * 2;
#pragma unroll
    for (int s = 0; s < 2; ++s)
#pragma unroll
      for (int ot = 0; ot < 2; ++ot)
        afr[s * 2 + ot] = *(const bf16x8*)(Ag2 + ((size_t)((ch + s) * 2 + ot) * 64 + lane) * 8);
  };

  int rdAddr0 = wv * 512 + (quad * 16 + (l16 ^ quad)) * 8;
  auto mfmaPhase = [&](int buf, int half) {
    const unsigned short* base = &sB[buf][half][0];
    __builtin_amdgcn_s_setprio(1);
#pragma unroll
    for (int s = 0; s < 2; ++s) {
      bf16x8 bfr = *(const bf16x8*)(base + s * 2048 + rdAddr0);
      acc[0] = __builtin_amdgcn_mfma_f32_16x16x32_bf16(afr[s * 2 + 0], bfr, acc[0], 0, 0, 0);
      acc[1] = __builtin_amdgcn_mfma_f32_16x16x32_bf16(afr[s * 2 + 1], bfr, acc[1], 0, 0, 0);
    }
    __builtin_amdgcn_s_setprio(0);
  };
  auto store = [&](uint4* d, int buf, int half) {
    *(uint4*)(&sB[buf][half][a0]) = d[0];
    *(uint4*)(&sB[buf][half][a1]) = d[1];
  };

  // prologue: stage g0,g1 into buf0; g2,g3 corners in flight
  issue(0, dA);
  issue(1, dB);
  aload(0);
  store(dA, 0, 0);
  issue(2, dA);
  store(dB, 0, 1);
  issue(3, dB);
  bar();

  for (int i = 0; i < NIV; ++i) {
    int buf = i & 1;
    mfmaPhase(buf, 0);                   // group 2i
    aload(2 * i + 1);
    if (i < NIV - 1) store(dA, buf ^ 1, 0);      // group 2i+2
    if (i < NIV - 2) issue(2 * i + 4, dA);
    mfmaPhase(buf, 1);                   // group 2i+1
    if (i < NIV - 1) store(dB, buf ^ 1, 1);      // group 2i+3
    if (i < NIV - 2) issue(2 * i + 5, dB);
    if (i < NIV - 1) aload(2 * i + 2);
    bar();
  }

  // Epilogue
  int pix = pixBase + wv * 16 + l16;
  int he = pix / W, we = pix % W;
#pragma unroll
  for (int ot = 0; ot < 2; ++ot) {
#pragma unroll
    for (int r = 0; r < 4; ++r) {
      int kk = ot * 16 + quad * 4 + r;
      if (kk >= 27) continue;
      float v = acc[ot][r] + b_off[kk];
      if (kk < 9) {
        py[(size_t)(n * 9 + kk) * HW + pix] = v + (float)he + (float)(kk / 3 - 1);
      } else if (kk < 18) {
        int j = kk - 9;
        px[(size_t)(n * 9 + j) * HW + pix] = v + (float)we + (float)(j % 3 - 1);
      } else {
        mk[(size_t)(n * 9 + (kk - 18)) * HW + pix] = 1.f / (1.f + expf(-v));
      }
    }
  }
}

// ---------------------------------------------------------------------------
// Kernel G: FUSED bilinear-sample + bf16 MFMA GEMM, 48-px tiles, BK=128.
// Grid = 192x4 = 768 blocks = EXACTLY 3 blocks/CU (uniform CU load).
// sB padded so LDS = 49664B -> HW cannot pack a 4th block on any CU.
// 6 waves stage (384 slots = 8 chunks x 3 pt x 16 px); all 8 waves MFMA.
// ---------------------------------------------------------------------------
__global__ __launch_bounds__(512, 4)
void fused_gemm(const unsigned short* __restrict__ xT,
                const unsigned short* __restrict__ Ag,
                const float* __restrict__ py,
                const float* __restrict__ px,
                const float* __restrict__ mk,
                unsigned short* __restrict__ yb,
                float* __restrict__ sumArr, float* __restrict__ sqArr) {
  __shared__ int   sIdx4[9][TPX][4];           // 6912 B
  __shared__ float sWgt4[9][TPX][4];           // 6912 B
  __shared__ unsigned short sB[2][2][4480];    // used: 3072/half; padded->3 blk/CU

  int tid = threadIdx.x;
  int wv = tid >> 6, lane = tid & 63, quad = lane >> 4, l16 = lane & 15;
  int pixBase = blockIdx.x * TPX;
  int n = blockIdx.y;
  const unsigned short* xTn = xT + (size_t)n * HW * CIN;

  // ---- prologue: corner indices + mask-folded weights, 48 px x 9 taps
  if (tid < 9 * TPX) {
    int k = tid / TPX, pix0 = tid - k * TPX;
    int off = (n * 9 + k) * HW + pixBase + pix0;
    float fy = py[off], fx = px[off], fm = mk[off];
    float y0f = floorf(fy), x0f = floorf(fx);
    float ly = fy - y0f, lx = fx - x0f;
    int y0 = (int)y0f, x0 = (int)x0f;
    int cy0 = min(max(y0, 0), H - 1), cy1 = min(max(y0 + 1, 0), H - 1);
    int cx0 = min(max(x0, 0), W - 1), cx1 = min(max(x0 + 1, 0), W - 1);
    float vy0 = (y0 >= 0 && y0 <= H - 1) ? 1.f : 0.f;
    float vy1 = (y0 + 1 >= 0 && y0 + 1 <= H - 1) ? 1.f : 0.f;
    float vx0 = (x0 >= 0 && x0 <= W - 1) ? 1.f : 0.f;
    float vx1 = (x0 + 1 >= 0 && x0 + 1 <= W - 1) ? 1.f : 0.f;
    int4 iv;
    iv.x = cy0 * W + cx0;
    iv.y = cy0 * W + cx1;
    iv.z = cy1 * W + cx0;
    iv.w = cy1 * W + cx1;
    float4 wf;
    wf.x = (1.f - ly) * (1.f - lx) * fm * vy0 * vx0;
    wf.y = (1.f - ly) * lx * fm * vy0 * vx1;
    wf.z = ly * (1.f - lx) * fm * vy1 * vx0;
    wf.w = ly * lx * fm * vy1 * vx1;
    *(int4*)(&sIdx4[k][pix0][0]) = iv;
    *(float4*)(&sWgt4[k][pix0][0]) = wf;
  }
  bar();

  // sampler role: waves 0-5; 4 consecutive lanes = 1 corner-row line
  int wvm3 = wv % 3, wvd3 = wv / 3;           // pt-tile, chunk-half (wv<6)
  bool samp = (wv < 6);
  int pixS  = (wvm3 << 4) | (lane >> 2);      // 0..47
  int qS    = lane & 3;
  int chunk = (wvd3 << 2) | qS;               // 0..7
  int co    = chunk * 8;
  int sAddr = (chunk >> 2) * 1536 + wvm3 * 512 + (qS * 16 + ((lane >> 2) ^ qS)) * 8;

  f32x4 acc[2][3];
#pragma unroll
  for (int i = 0; i < 2; ++i)
#pragma unroll
    for (int pt = 0; pt < 3; ++pt) acc[i][pt] = (f32x4){0.f, 0.f, 0.f, 0.f};

  uint4 cnA[4], cnB[4];
  float wgA[4], wgB[4];
  auto issue = [&](int g, uint4* cn, float* wt) {
    int k = g % 9, c2 = g / 9;
    int4 iv = *(const int4*)(&sIdx4[k][pixS][0]);
    float4 wf = *(const float4*)(&sWgt4[k][pixS][0]);
    int coff = c2 * 64 + co;
    cn[0] = *(const uint4*)(xTn + (size_t)iv.x * CIN + coff);
    cn[1] = *(const uint4*)(xTn + (size_t)iv.y * CIN + coff);
    cn[2] = *(const uint4*)(xTn + (size_t)iv.z * CIN + coff);
    cn[3] = *(const uint4*)(xTn + (size_t)iv.w * CIN + coff);
    wt[0] = wf.x; wt[1] = wf.y; wt[2] = wf.z; wt[3] = wf.w;
  };

  auto blendOne = [&](unsigned int u0, unsigned int u1, unsigned int u2,
                      unsigned int u3, const float* wt) -> unsigned int {
    f32x2 s = up2(u0) * wt[0];       // v_pk_fma chain
    s += up2(u1) * wt[1];
    s += up2(u2) * wt[2];
    s += up2(u3) * wt[3];
    return cvtpk(s.x, s.y);          // 1-instr RNE pack
  };
  auto blendStore = [&](uint4* cn, const float* wt, int buf, int half) {
    uint4 r;
    r.x = blendOne(cn[0].x, cn[1].x, cn[2].x, cn[3].x, wt);
    r.y = blendOne(cn[0].y, cn[1].y, cn[2].y, cn[3].y, wt);
    r.z = blendOne(cn[0].z, cn[1].z, cn[2].z, cn[3].z, wt);
    r.w = blendOne(cn[0].w, cn[1].w, cn[2].w, cn[3].w, wt);
    *(uint4*)(&sB[buf][half][sAddr]) = r;
  };

  bf16x8 afr[4];
  auto aload = [&](int g) {
    int k = g % 9, c2 = g / 9;
    int ch = k * 8 + c2 * 2;
#pragma unroll
    for (int s = 0; s < 2; ++s)
#pragma unroll
      for (int ot = 0; ot < 2; ++ot)
        afr[s * 2 + ot] = *(const bf16x8*)(Ag + ((size_t)((ch + s) * 16 + 2 * wv + ot) * 64 + lane) * 8);
  };

  int rdBase = (quad * 16 + (l16 ^ quad)) * 8;
  auto mfmaPhase = [&](int buf, int half) {
    const unsigned short* base = &sB[buf][half][0];
    __builtin_amdgcn_s_setprio(1);
#pragma unroll
    for (int s = 0; s < 2; ++s) {
      bf16x8 bfr[3];
#pragma unroll
      for (int pt = 0; pt < 3; ++pt)
        bfr[pt] = *(const bf16x8*)(base + s * 1536 + pt * 512 + rdBase);
#pragma unroll
      for (int pt = 0; pt < 3; ++pt) {
        acc[0][pt] = __builtin_amdgcn_mfma_f32_16x16x32_bf16(afr[s * 2 + 0], bfr[pt], acc[0][pt], 0, 0, 0);
        acc[1][pt] = __builtin_amdgcn_mfma_f32_16x16x32_bf16(afr[s * 2 + 1], bfr[pt], acc[1][pt], 0, 0, 0);
      }
    }
    __builtin_amdgcn_s_setprio(0);
  };

  // prologue: stage g0,g1 into buf0; g2,g3 corners in flight across bar
  if (samp) {
    issue(0, cnA, wgA);
    issue(1, cnB, wgB);
  }
  aload(0);
  if (samp) {
    blendStore(cnA, wgA, 0, 0);
    issue(2, cnA, wgA);
    blendStore(cnB, wgB, 0, 1);
    issue(3, cnB, wgB);
  }
  bar();

  for (int i = 0; i < NIV; ++i) {
    int buf = i & 1;
    mfmaPhase(buf, 0);                        // group 2i
    aload(2 * i + 1);
    if (samp && i < NIV - 1) blendStore(cnA, wgA, buf ^ 1, 0);   // group 2i+2
    if (samp && i < NIV - 2) issue(2 * i + 4, cnA, wgA);
    mfmaPhase(buf, 1);                        // group 2i+1
    if (samp && i < NIV - 1) blendStore(cnB, wgB, buf ^ 1, 1);   // group 2i+3
    if (samp && i < NIV - 2) issue(2 * i + 5, cnB, wgB);
    if (i < NIV - 1) aload(2 * i + 2);
    bar();
  }

  // Epilogue: D col = l16 (pix), row = quad*4 + r (o within 16-tile)
#pragma unroll
  for (int ot = 0; ot < 2; ++ot) {
#pragma unroll
    for (int r = 0; r < 4; ++r) {
      int o = (2 * wv + ot) * 16 + quad * 4 + r;
      unsigned short* rowp = yb + (size_t)(n * COUT + o) * HW + pixBase;
      float s = 0.f, q = 0.f;
#pragma unroll
      for (int pt = 0; pt < 3; ++pt) {
        float v = acc[ot][pt][r];
        rowp[pt * 16 + l16] = f2bf(v);
        s += v;
        q = fmaf(v, v, q);
      }
#pragma unroll
      for (int m = 8; m >= 1; m >>= 1) {
        s += __shfl_xor(s, m, 64);
        q += __shfl_xor(q, m, 64);
      }
      if (l16 == 0) {
        atomicAdd(&sumArr[o], s);
        atomicAdd(&sqArr[o], q);
      }
    }
  }
}

// ---------------------------------------------------------------------------
// BN apply with inlined finalize (bf16 y -> fp32 out).
// ---------------------------------------------------------------------------
__global__ __launch_bounds__(256)
void bn_apply(const unsigned short* __restrict__ yb,
              float* __restrict__ out,
              const float* __restrict__ sumArr,
              const float* __restrict__ sqArr,
              const float* __restrict__ gamma,
              const float* __restrict__ beta) {
  int gid = blockIdx.x * 256 + threadIdx.x;  // < NB*COUT*HW/8
  int base = gid * 8;
  int o = (base / HW) % COUT;
  const float inv = 1.f / (float)(NB * HW);
  float mean = sumArr[o] * inv;
  float var = sqArr[o] * inv - mean * mean;
  float scale = rsqrtf(var + 1e-5f) * gamma[o];
  float shift = beta[o] - mean * scale;
  uint4 v = ((const uint4*)yb)[gid];
  float4 a, b;
  a.x = fmaxf(fmaf(bf2f((unsigned short)(v.x & 0xffff)), scale, shift), 0.f);
  a.y = fmaxf(fmaf(bf2f((unsigned short)(v.x >> 16)), scale, shift), 0.f);
  a.z = fmaxf(fmaf(bf2f((unsigned short)(v.y & 0xffff)), scale, shift), 0.f);
  a.w = fmaxf(fmaf(bf2f((unsigned short)(v.y >> 16)), scale, shift), 0.f);
  b.x = fmaxf(fmaf(bf2f((unsigned short)(v.z & 0xffff)), scale, shift), 0.f);
  b.y = fmaxf(fmaf(bf2f((unsigned short)(v.z >> 16)), scale, shift), 0.f);
  b.z = fmaxf(fmaf(bf2f((unsigned short)(v.w & 0xffff)), scale, shift), 0.f);
  b.w = fmaxf(fmaf(bf2f((unsigned short)(v.w >> 16)), scale, shift), 0.f);
  *(float4*)&out[base] = a;
  *(float4*)&out[base + 4] = b;
}

// ---------------------------------------------------------------------------
extern "C" void kernel_launch(void* const* d_in, const int* in_sizes, int n_in,
                              void* d_out, int out_size, void* d_ws, size_t ws_size,
                              hipStream_t stream) {
  const float* x     = (const float*)d_in[0];
  const float* w_off = (const float*)d_in[1];
  const float* b_off = (const float*)d_in[2];
  const float* w     = (const float*)d_in[3];
  // d_in[4] = b : cancels exactly in BN mean-subtraction
  const float* gamma = (const float*)d_in[5];
  const float* beta  = (const float*)d_in[6];
  float* out = (float*)d_out;

  float* ws = (float*)d_ws;
  float* py = ws;                          // 331776 f
  float* px = py + 331776;
  float* mk = px + 331776;
  unsigned short* Ag  = (unsigned short*)(mk + 331776);  // 589824 u16
  unsigned short* Ag2 = Ag + 589824;                     // 73728 u16
  float* sumArr   = (float*)(Ag2 + 73728);
  float* sqArr    = sumArr + 256;                        // contiguous after sumArr
  unsigned short* yb = (unsigned short*)(sqArr + 256);   // 9437184 u16
  unsigned short* xT = yb + 9437184;                     // 9437184 u16

  prep<<<2629, 256, 0, stream>>>(x, xT, w, w_off, Ag, Ag2, sumArr);

  dim3 gO(HW / 64, NB);
  offset_gemm<<<gO, 256, 0, stream>>>(xT, Ag2, b_off, py, px, mk);

  dim3 gG(HW / TPX, NB);
  fused_gemm<<<gG, 512, 0, stream>>>(xT, Ag, py, px, mk, yb, sumArr, sqArr);

  bn_apply<<<(NB * COUT * HW / 8) / 256, 256, 0, stream>>>(yb, out, sumArr, sqArr, gamma, beta);
}

// Round 15
// 251.940 us; speedup vs baseline: 1.0955x; 1.0082x over previous
//
#include <hip/hip_runtime.h>
#include <cmath>

#define H 96
#define W 96
#define HW 9216
#define CIN 256
#define COUT 256
#define NB 4
#define NCH 72   // K-chunks of 32 kc
#define NGR 36   // K-groups of 64 kc: g = c2*9 + k (c2-OUTER, k-inner: L1-friendly)
#define NIV 18   // intervals of 2 groups (BK=128): one barrier each
#define TPX 48   // fused_gemm pixel tile: 192 tiles x 4 n = 768 blocks = 3/CU EXACTLY

// NOTE (r13): hipLaunchCooperativeKernel silently failed in this harness
// (output never written; absmax == max|ref|). Do NOT use grid.sync() here.
// NOTE (r12): BK=192 spilled (3rd corner-buffer set; WRITE 24.6->67MB) — BK=128 is the register ceiling.
// NOTE (r8): never request >4 waves/EU via launch_bounds — 64-reg budget => 2.8GB scratch, 780us.
// NOTE (r15): s_setprio removed — isolated A/B. It was added bundled (r3) and never
// isolated; learn_hip m190 measured setprio ~0 to NEGATIVE on barrier-lockstep GEMM
// (only helps role-split 8-phase schedules). Our intervals are lockstep.

typedef float f32x4 __attribute__((ext_vector_type(4)));
typedef float f32x2 __attribute__((ext_vector_type(2)));
typedef short bf16x8 __attribute__((ext_vector_type(8)));

__device__ __forceinline__ unsigned short f2bf(float f) {
  unsigned int u = __float_as_uint(f);
  u += 0x7fff + ((u >> 16) & 1);  // round-to-nearest-even
  return (unsigned short)(u >> 16);
}
__device__ __forceinline__ float bf2f(unsigned short u) {
  return __uint_as_float(((unsigned int)u) << 16);
}
__device__ __forceinline__ f32x2 up2(unsigned int u) {
  f32x2 r;
  r.x = __uint_as_float(u << 16);
  r.y = __uint_as_float(u & 0xffff0000u);
  return r;
}
// one-instr RNE pack of two f32 -> packed bf16x2
__device__ __forceinline__ unsigned int cvtpk(float lo, float hi) {
  unsigned int r;
  asm("v_cvt_pk_bf16_f32 %0, %1, %2" : "=v"(r) : "v"(lo), "v"(hi));
  return r;
}

// Raw barrier with LDS-only drain (keeps global loads in flight).
__device__ __forceinline__ void bar() {
  asm volatile("s_waitcnt lgkmcnt(0)" ::: "memory");
  __builtin_amdgcn_s_barrier();
  asm volatile("" ::: "memory");
}

// ---------------------------------------------------------------------------
// Kernel P: PREP = xt_convert (blocks 0..2303) + wa_all (blocks 2304..2628).
// ---------------------------------------------------------------------------
__global__ __launch_bounds__(256)
void prep(const float* __restrict__ x, unsigned short* __restrict__ xT,
          const float* __restrict__ w, const float* __restrict__ w_off,
          unsigned short* __restrict__ Ag, unsigned short* __restrict__ Ag2,
          float* __restrict__ sumArr) {
  __shared__ unsigned short ls[64][72];
  int bx = blockIdx.x;
  int tid = threadIdx.x;

  if (bx < 2304) {
    // ---- xt_convert: bx = n*576 + cb*144 + hwt
    int n   = bx / 576;
    int rem = bx - n * 576;
    int cb  = rem / 144;
    int hwt = rem - cb * 144;
    int hwbase = hwt * 64;
    int cbase  = cb * 64;
    {
      int cl = tid >> 2, qd = tid & 3;
      const float* src = x + ((size_t)(n * CIN + cbase + cl)) * HW + hwbase + qd * 16;
#pragma unroll
      for (int m = 0; m < 4; ++m) {
        float4 v = *(const float4*)(src + m * 4);
        int hwl = qd * 16 + m * 4;
        ls[hwl + 0][cl] = f2bf(v.x);
        ls[hwl + 1][cl] = f2bf(v.y);
        ls[hwl + 2][cl] = f2bf(v.z);
        ls[hwl + 3][cl] = f2bf(v.w);
      }
    }
    __syncthreads();
    {
      int hw = tid >> 2, part = tid & 3;
      unsigned short* dst = xT + ((size_t)(n * HW + hwbase + hw)) * CIN + cbase + part * 16;
      *(uint4*)(dst + 0) = *(const uint4*)(&ls[hw][part * 16 + 0]);
      *(uint4*)(dst + 8) = *(const uint4*)(&ls[hw][part * 16 + 8]);
    }
  } else if (bx < 2592) {    // ---- main weights: 288 blocks
    int gid = (bx - 2304) * 256 + tid;
    int ch = gid >> 10;
    int rest = gid & 1023;
    int ot = rest >> 6, l = rest & 63;
    int o = ot * 16 + (l & 15);
    int k = ch >> 3, cc = ch & 7;
    int cbase = cc * 32 + (l >> 4) * 8;
    unsigned short r[8];
#pragma unroll
    for (int j = 0; j < 8; ++j)
      r[j] = f2bf(w[((size_t)o * CIN + cbase + j) * 9 + k]);
    uint4 pk;
    pk.x = (unsigned int)r[0] | ((unsigned int)r[1] << 16);
    pk.y = (unsigned int)r[2] | ((unsigned int)r[3] << 16);
    pk.z = (unsigned int)r[4] | ((unsigned int)r[5] << 16);
    pk.w = (unsigned int)r[6] | ((unsigned int)r[7] << 16);
    *(uint4*)(Ag + (size_t)gid * 8) = pk;
  } else if (bx < 2628) {    // ---- offset weights: 36 blocks
    int gid = (bx - 2592) * 256 + tid;
    int ch = gid >> 7;
    int rest = gid & 127;
    int ot = rest >> 6, l = rest & 63;
    int o = ot * 16 + (l & 15);
    int k = ch >> 3, cc = ch & 7;
    int cbase = cc * 32 + (l >> 4) * 8;
    unsigned short r[8];
#pragma unroll
    for (int j = 0; j < 8; ++j)
      r[j] = (o < 27) ? f2bf(w_off[((size_t)o * CIN + cbase + j) * 9 + k]) : (unsigned short)0;
    uint4 pk;
    pk.x = (unsigned int)r[0] | ((unsigned int)r[1] << 16);
    pk.y = (unsigned int)r[2] | ((unsigned int)r[3] << 16);
    pk.z = (unsigned int)r[4] | ((unsigned int)r[5] << 16);
    pk.w = (unsigned int)r[6] | ((unsigned int)r[7] << 16);
    *(uint4*)(Ag2 + (size_t)gid * 8) = pk;
  } else {                   // ---- zero sumArr[256] + sqArr[256] (contiguous)
    sumArr[tid] = 0.f;
    sumArr[256 + tid] = 0.f;
  }
}

// ---------------------------------------------------------------------------
// Kernel O: offset conv bf16 MFMA GEMM, BK=128 intervals, depth-2 prefetch.
// 256 threads, 64-px tiles; short (~23us).
// ---------------------------------------------------------------------------
__global__ __launch_bounds__(256, 4)
void offset_gemm(const unsigned short* __restrict__ xT,
                 const unsigned short* __restrict__ Ag2,
                 const float* __restrict__ b_off,
                 float* __restrict__ py, float* __restrict__ px,
                 float* __restrict__ mk) {
  __shared__ int sPos[9][64];
  __shared__ unsigned short sB[2][2][4096];  // [bufpair][group-half][64px*64kc]

  int tid = threadIdx.x;
  int wv = tid >> 6, lane = tid & 63, quad = lane >> 4, l16 = lane & 15;
  int pixBase = blockIdx.x * 64;
  int n = blockIdx.y;
  const unsigned short* xTn = xT + (size_t)n * HW * CIN;

  if (tid < 64) {
    int hwp = pixBase + tid;
    int hh = hwp / W, wx = hwp % W;
#pragma unroll
    for (int ty = 0; ty < 3; ++ty) {
#pragma unroll
      for (int tx = 0; tx < 3; ++tx) {
        int iy = hh + ty - 1, ix = wx + tx - 1;
        bool ok = (iy >= 0) && (iy < H) && (ix >= 0) && (ix < W);
        sPos[ty * 3 + tx][tid] = ok ? (iy * W + ix) : -1;
      }
    }
  }
  bar();

  int pix0 = tid >> 3, ck0 = tid & 7;
  int pix1 = 32 + (tid >> 3);
  int a0 = (ck0 >> 2) * 2048 + (pix0 >> 4) * 512 + ((ck0 & 3) * 16 + ((pix0 & 15) ^ (ck0 & 3))) * 8;
  int a1 = (ck0 >> 2) * 2048 + (pix1 >> 4) * 512 + ((ck0 & 3) * 16 + ((pix1 & 15) ^ (ck0 & 3))) * 8;

  f32x4 acc[2];
  acc[0] = (f32x4){0.f, 0.f, 0.f, 0.f};
  acc[1] = (f32x4){0.f, 0.f, 0.f, 0.f};

  uint4 dA[2], dB[2];
  auto issue = [&](int g, uint4* d) {
    int k = g % 9, c2 = g / 9;
    int p0 = sPos[k][pix0], p1 = sPos[k][pix1];
    d[0] = (uint4){0, 0, 0, 0};
    d[1] = (uint4){0, 0, 0, 0};
    if (p0 >= 0) d[0] = *(const uint4*)(xTn + (size_t)p0 * CIN + c2 * 64 + ck0 * 8);
    if (p1 >= 0) d[1] = *(const uint4*)(xTn + (size_t)p1 * CIN + c2 * 64 + ck0 * 8);
  };

  bf16x8 afr[4];
  auto aload = [&](int g) {
    int k = g % 9, c2 = g / 9;
    int ch = k * 8 + c2 * 2;
#pragma unroll
    for (int s = 0; s < 2; ++s)
#pragma unroll
      for (int ot = 0; ot < 2; ++ot)
        afr[s * 2 + ot] = *(const bf16x8*)(Ag2 + ((size_t)((ch + s) * 2 + ot) * 64 + lane) * 8);
  };

  int rdAddr0 = wv * 512 + (quad * 16 + (l16 ^ quad)) * 8;
  auto mfmaPhase = [&](int buf, int half) {
    const unsigned short* base = &sB[buf][half][0];
#pragma unroll
    for (int s = 0; s < 2; ++s) {
      bf16x8 bfr = *(const bf16x8*)(base + s * 2048 + rdAddr0);
      acc[0] = __builtin_amdgcn_mfma_f32_16x16x32_bf16(afr[s * 2 + 0], bfr, acc[0], 0, 0, 0);
      acc[1] = __builtin_amdgcn_mfma_f32_16x16x32_bf16(afr[s * 2 + 1], bfr, acc[1], 0, 0, 0);
    }
  };
  auto store = [&](uint4* d, int buf, int half) {
    *(uint4*)(&sB[buf][half][a0]) = d[0];
    *(uint4*)(&sB[buf][half][a1]) = d[1];
  };

  // prologue: stage g0,g1 into buf0; g2,g3 corners in flight
  issue(0, dA);
  issue(1, dB);
  aload(0);
  store(dA, 0, 0);
  issue(2, dA);
  store(dB, 0, 1);
  issue(3, dB);
  bar();

  for (int i = 0; i < NIV; ++i) {
    int buf = i & 1;
    mfmaPhase(buf, 0);                   // group 2i
    aload(2 * i + 1);
    if (i < NIV - 1) store(dA, buf ^ 1, 0);      // group 2i+2
    if (i < NIV - 2) issue(2 * i + 4, dA);
    mfmaPhase(buf, 1);                   // group 2i+1
    if (i < NIV - 1) store(dB, buf ^ 1, 1);      // group 2i+3
    if (i < NIV - 2) issue(2 * i + 5, dB);
    if (i < NIV - 1) aload(2 * i + 2);
    bar();
  }

  // Epilogue
  int pix = pixBase + wv * 16 + l16;
  int he = pix / W, we = pix % W;
#pragma unroll
  for (int ot = 0; ot < 2; ++ot) {
#pragma unroll
    for (int r = 0; r < 4; ++r) {
      int kk = ot * 16 + quad * 4 + r;
      if (kk >= 27) continue;
      float v = acc[ot][r] + b_off[kk];
      if (kk < 9) {
        py[(size_t)(n * 9 + kk) * HW + pix] = v + (float)he + (float)(kk / 3 - 1);
      } else if (kk < 18) {
        int j = kk - 9;
        px[(size_t)(n * 9 + j) * HW + pix] = v + (float)we + (float)(j % 3 - 1);
      } else {
        mk[(size_t)(n * 9 + (kk - 18)) * HW + pix] = 1.f / (1.f + expf(-v));
      }
    }
  }
}

// ---------------------------------------------------------------------------
// Kernel G: FUSED bilinear-sample + bf16 MFMA GEMM, 48-px tiles, BK=128.
// Grid = 192x4 = 768 blocks = EXACTLY 3 blocks/CU (uniform CU load).
// sB padded so LDS = 49664B -> HW cannot pack a 4th block on any CU.
// 6 waves stage (384 slots = 8 chunks x 3 pt x 16 px); all 8 waves MFMA.
// ---------------------------------------------------------------------------
__global__ __launch_bounds__(512, 4)
void fused_gemm(const unsigned short* __restrict__ xT,
                const unsigned short* __restrict__ Ag,
                const float* __restrict__ py,
                const float* __restrict__ px,
                const float* __restrict__ mk,
                unsigned short* __restrict__ yb,
                float* __restrict__ sumArr, float* __restrict__ sqArr) {
  __shared__ int   sIdx4[9][TPX][4];           // 6912 B
  __shared__ float sWgt4[9][TPX][4];           // 6912 B
  __shared__ unsigned short sB[2][2][4480];    // used: 3072/half; padded->3 blk/CU

  int tid = threadIdx.x;
  int wv = tid >> 6, lane = tid & 63, quad = lane >> 4, l16 = lane & 15;
  int pixBase = blockIdx.x * TPX;
  int n = blockIdx.y;
  const unsigned short* xTn = xT + (size_t)n * HW * CIN;

  // ---- prologue: corner indices + mask-folded weights, 48 px x 9 taps
  if (tid < 9 * TPX) {
    int k = tid / TPX, pix0 = tid - k * TPX;
    int off = (n * 9 + k) * HW + pixBase + pix0;
    float fy = py[off], fx = px[off], fm = mk[off];
    float y0f = floorf(fy), x0f = floorf(fx);
    float ly = fy - y0f, lx = fx - x0f;
    int y0 = (int)y0f, x0 = (int)x0f;
    int cy0 = min(max(y0, 0), H - 1), cy1 = min(max(y0 + 1, 0), H - 1);
    int cx0 = min(max(x0, 0), W - 1), cx1 = min(max(x0 + 1, 0), W - 1);
    float vy0 = (y0 >= 0 && y0 <= H - 1) ? 1.f : 0.f;
    float vy1 = (y0 + 1 >= 0 && y0 + 1 <= H - 1) ? 1.f : 0.f;
    float vx0 = (x0 >= 0 && x0 <= W - 1) ? 1.f : 0.f;
    float vx1 = (x0 + 1 >= 0 && x0 + 1 <= W - 1) ? 1.f : 0.f;
    int4 iv;
    iv.x = cy0 * W + cx0;
    iv.y = cy0 * W + cx1;
    iv.z = cy1 * W + cx0;
    iv.w = cy1 * W + cx1;
    float4 wf;
    wf.x = (1.f - ly) * (1.f - lx) * fm * vy0 * vx0;
    wf.y = (1.f - ly) * lx * fm * vy0 * vx1;
    wf.z = ly * (1.f - lx) * fm * vy1 * vx0;
    wf.w = ly * lx * fm * vy1 * vx1;
    *(int4*)(&sIdx4[k][pix0][0]) = iv;
    *(float4*)(&sWgt4[k][pix0][0]) = wf;
  }
  bar();

  // sampler role: waves 0-5; 4 consecutive lanes = 1 corner-row line
  int wvm3 = wv % 3, wvd3 = wv / 3;           // pt-tile, chunk-half (wv<6)
  bool samp = (wv < 6);
  int pixS  = (wvm3 << 4) | (lane >> 2);      // 0..47
  int qS    = lane & 3;
  int chunk = (wvd3 << 2) | qS;               // 0..7
  int co    = chunk * 8;
  int sAddr = (chunk >> 2) * 1536 + wvm3 * 512 + (qS * 16 + ((lane >> 2) ^ qS)) * 8;

  f32x4 acc[2][3];
#pragma unroll
  for (int i = 0; i < 2; ++i)
#pragma unroll
    for (int pt = 0; pt < 3; ++pt) acc[i][pt] = (f32x4){0.f, 0.f, 0.f, 0.f};

  uint4 cnA[4], cnB[4];
  float wgA[4], wgB[4];
  auto issue = [&](int g, uint4* cn, float* wt) {
    int k = g % 9, c2 = g / 9;
    int4 iv = *(const int4*)(&sIdx4[k][pixS][0]);
    float4 wf = *(const float4*)(&sWgt4[k][pixS][0]);
    int coff = c2 * 64 + co;
    cn[0] = *(const uint4*)(xTn + (size_t)iv.x * CIN + coff);
    cn[1] = *(const uint4*)(xTn + (size_t)iv.y * CIN + coff);
    cn[2] = *(const uint4*)(xTn + (size_t)iv.z * CIN + coff);
    cn[3] = *(const uint4*)(xTn + (size_t)iv.w * CIN + coff);
    wt[0] = wf.x; wt[1] = wf.y; wt[2] = wf.z; wt[3] = wf.w;
  };

  auto blendOne = [&](unsigned int u0, unsigned int u1, unsigned int u2,
                      unsigned int u3, const float* wt) -> unsigned int {
    f32x2 s = up2(u0) * wt[0];       // v_pk_fma chain
    s += up2(u1) * wt[1];
    s += up2(u2) * wt[2];
    s += up2(u3) * wt[3];
    return cvtpk(s.x, s.y);          // 1-instr RNE pack
  };
  auto blendStore = [&](uint4* cn, const float* wt, int buf, int half) {
    uint4 r;
    r.x = blendOne(cn[0].x, cn[1].x, cn[2].x, cn[3].x, wt);
    r.y = blendOne(cn[0].y, cn[1].y, cn[2].y, cn[3].y, wt);
    r.z = blendOne(cn[0].z, cn[1].z, cn[2].z, cn[3].z, wt);
    r.w = blendOne(cn[0].w, cn[1].w, cn[2].w, cn[3].w, wt);
    *(uint4*)(&sB[buf][half][sAddr]) = r;
  };

  bf16x8 afr[4];
  auto aload = [&](int g) {
    int k = g % 9, c2 = g / 9;
    int ch = k * 8 + c2 * 2;
#pragma unroll
    for (int s = 0; s < 2; ++s)
#pragma unroll
      for (int ot = 0; ot < 2; ++ot)
        afr[s * 2 + ot] = *(const bf16x8*)(Ag + ((size_t)((ch + s) * 16 + 2 * wv + ot) * 64 + lane) * 8);
  };

  int rdBase = (quad * 16 + (l16 ^ quad)) * 8;
  auto mfmaPhase = [&](int buf, int half) {
    const unsigned short* base = &sB[buf][half][0];
#pragma unroll
    for (int s = 0; s < 2; ++s) {
      bf16x8 bfr[3];
#pragma unroll
      for (int pt = 0; pt < 3; ++pt)
        bfr[pt] = *(const bf16x8*)(base + s * 1536 + pt * 512 + rdBase);
#pragma unroll
      for (int pt = 0; pt < 3; ++pt) {
        acc[0][pt] = __builtin_amdgcn_mfma_f32_16x16x32_bf16(afr[s * 2 + 0], bfr[pt], acc[0][pt], 0, 0, 0);
        acc[1][pt] = __builtin_amdgcn_mfma_f32_16x16x32_bf16(afr[s * 2 + 1], bfr[pt], acc[1][pt], 0, 0, 0);
      }
    }
  };

  // prologue: stage g0,g1 into buf0; g2,g3 corners in flight across bar
  if (samp) {
    issue(0, cnA, wgA);
    issue(1, cnB, wgB);
  }
  aload(0);
  if (samp) {
    blendStore(cnA, wgA, 0, 0);
    issue(2, cnA, wgA);
    blendStore(cnB, wgB, 0, 1);
    issue(3, cnB, wgB);
  }
  bar();

  for (int i = 0; i < NIV; ++i) {
    int buf = i & 1;
    mfmaPhase(buf, 0);                        // group 2i
    aload(2 * i + 1);
    if (samp && i < NIV - 1) blendStore(cnA, wgA, buf ^ 1, 0);   // group 2i+2
    if (samp && i < NIV - 2) issue(2 * i + 4, cnA, wgA);
    mfmaPhase(buf, 1);                        // group 2i+1
    if (samp && i < NIV - 1) blendStore(cnB, wgB, buf ^ 1, 1);   // group 2i+3
    if (samp && i < NIV - 2) issue(2 * i + 5, cnB, wgB);
    if (i < NIV - 1) aload(2 * i + 2);
    bar();
  }

  // Epilogue: D col = l16 (pix), row = quad*4 + r (o within 16-tile)
#pragma unroll
  for (int ot = 0; ot < 2; ++ot) {
#pragma unroll
    for (int r = 0; r < 4; ++r) {
      int o = (2 * wv + ot) * 16 + quad * 4 + r;
      unsigned short* rowp = yb + (size_t)(n * COUT + o) * HW + pixBase;
      float s = 0.f, q = 0.f;
#pragma unroll
      for (int pt = 0; pt < 3; ++pt) {
        float v = acc[ot][pt][r];
        rowp[pt * 16 + l16] = f2bf(v);
        s += v;
        q = fmaf(v, v, q);
      }
#pragma unroll
      for (int m = 8; m >= 1; m >>= 1) {
        s += __shfl_xor(s, m, 64);
        q += __shfl_xor(q, m, 64);
      }
      if (l16 == 0) {
        atomicAdd(&sumArr[o], s);
        atomicAdd(&sqArr[o], q);
      }
    }
  }
}

// ---------------------------------------------------------------------------
// BN apply with inlined finalize (bf16 y -> fp32 out).
// ---------------------------------------------------------------------------
__global__ __launch_bounds__(256)
void bn_apply(const unsigned short* __restrict__ yb,
              float* __restrict__ out,
              const float* __restrict__ sumArr,
              const float* __restrict__ sqArr,
              const float* __restrict__ gamma,
              const float* __restrict__ beta) {
  int gid = blockIdx.x * 256 + threadIdx.x;  // < NB*COUT*HW/8
  int base = gid * 8;
  int o = (base / HW) % COUT;
  const float inv = 1.f / (float)(NB * HW);
  float mean = sumArr[o] * inv;
  float var = sqArr[o] * inv - mean * mean;
  float scale = rsqrtf(var + 1e-5f) * gamma[o];
  float shift = beta[o] - mean * scale;
  uint4 v = ((const uint4*)yb)[gid];
  float4 a, b;
  a.x = fmaxf(fmaf(bf2f((unsigned short)(v.x & 0xffff)), scale, shift), 0.f);
  a.y = fmaxf(fmaf(bf2f((unsigned short)(v.x >> 16)), scale, shift), 0.f);
  a.z = fmaxf(fmaf(bf2f((unsigned short)(v.y & 0xffff)), scale, shift), 0.f);
  a.w = fmaxf(fmaf(bf2f((unsigned short)(v.y >> 16)), scale, shift), 0.f);
  b.x = fmaxf(fmaf(bf2f((unsigned short)(v.z & 0xffff)), scale, shift), 0.f);
  b.y = fmaxf(fmaf(bf2f((unsigned short)(v.z >> 16)), scale, shift), 0.f);
  b.z = fmaxf(fmaf(bf2f((unsigned short)(v.w & 0xffff)), scale, shift), 0.f);
  b.w = fmaxf(fmaf(bf2f((unsigned short)(v.w >> 16)), scale, shift), 0.f);
  *(float4*)&out[base] = a;
  *(float4*)&out[base + 4] = b;
}

// ---------------------------------------------------------------------------
extern "C" void kernel_launch(void* const* d_in, const int* in_sizes, int n_in,
                              void* d_out, int out_size, void* d_ws, size_t ws_size,
                              hipStream_t stream) {
  const float* x     = (const float*)d_in[0];
  const float* w_off = (const float*)d_in[1];
  const float* b_off = (const float*)d_in[2];
  const float* w     = (const float*)d_in[3];
  // d_in[4] = b : cancels exactly in BN mean-subtraction
  const float* gamma = (const float*)d_in[5];
  const float* beta  = (const float*)d_in[6];
  float* out = (float*)d_out;

  float* ws = (float*)d_ws;
  float* py = ws;                          // 331776 f
  float* px = py + 331776;
  float* mk = px + 331776;
  unsigned short* Ag  = (unsigned short*)(mk + 331776);  // 589824 u16
  unsigned short* Ag2 = Ag + 589824;                     // 73728 u16
  float* sumArr   = (float*)(Ag2 + 73728);
  float* sqArr    = sumArr + 256;                        // contiguous after sumArr
  unsigned short* yb = (unsigned short*)(sqArr + 256);   // 9437184 u16
  unsigned short* xT = yb + 9437184;                     // 9437184 u16

  prep<<<2629, 256, 0, stream>>>(x, xT, w, w_off, Ag, Ag2, sumArr);

  dim3 gO(HW / 64, NB);
  offset_gemm<<<gO, 256, 0, stream>>>(xT, Ag2, b_off, py, px, mk);

  dim3 gG(HW / TPX, NB);
  fused_gemm<<<gG, 512, 0, stream>>>(xT, Ag, py, px, mk, yb, sumArr, sqArr);

  bn_apply<<<(NB * COUT * HW / 8) / 256, 256, 0, stream>>>(yb, out, sumArr, sqArr, gamma, beta);
}

// Round 16
// 243.775 us; speedup vs baseline: 1.1322x; 1.0335x over previous
//
#include <hip/hip_runtime.h>
#include <cmath>

#define H 96
#define W 96
#define HW 9216
#define CIN 256
#define COUT 256
#define NB 4
#define NCH 72   // K-chunks of 32 kc
#define NGR 36   // K-groups of 64 kc: g = c2*9 + k (c2-OUTER, k-inner: L1-friendly)
#define NIV 18   // intervals of 2 groups (BK=128): one barrier each
#define TPX 48   // fused_gemm pixel tile: 192 tiles x 4 n = 768 blocks = 3/CU EXACTLY

// NOTE (r13): hipLaunchCooperativeKernel silently failed in this harness
// (output never written; absmax == max|ref|). Do NOT use grid.sync() here.
// NOTE (r12): BK=192 spilled (3rd corner-buffer set; WRITE 24.6->67MB) — BK=128 is the register ceiling.
// NOTE (r8): never request >4 waves/EU via launch_bounds — 64-reg budget => 2.8GB scratch, 780us.
// NOTE (r15): s_setprio removed (isolated A/B: 129.1->125.9us, matches learn_hip m190).
// NOTE (r16): T1 XCD swizzle — consecutive tiles share halo; give each XCD a
// contiguous tile chunk so halo lines hit its private L2 (4MB; chunk ~2.4MB).

typedef float f32x4 __attribute__((ext_vector_type(4)));
typedef float f32x2 __attribute__((ext_vector_type(2)));
typedef short bf16x8 __attribute__((ext_vector_type(8)));

__device__ __forceinline__ unsigned short f2bf(float f) {
  unsigned int u = __float_as_uint(f);
  u += 0x7fff + ((u >> 16) & 1);  // round-to-nearest-even
  return (unsigned short)(u >> 16);
}
__device__ __forceinline__ float bf2f(unsigned short u) {
  return __uint_as_float(((unsigned int)u) << 16);
}
__device__ __forceinline__ f32x2 up2(unsigned int u) {
  f32x2 r;
  r.x = __uint_as_float(u << 16);
  r.y = __uint_as_float(u & 0xffff0000u);
  return r;
}
// one-instr RNE pack of two f32 -> packed bf16x2
__device__ __forceinline__ unsigned int cvtpk(float lo, float hi) {
  unsigned int r;
  asm("v_cvt_pk_bf16_f32 %0, %1, %2" : "=v"(r) : "v"(lo), "v"(hi));
  return r;
}

// Raw barrier with LDS-only drain (keeps global loads in flight).
__device__ __forceinline__ void bar() {
  asm volatile("s_waitcnt lgkmcnt(0)" ::: "memory");
  __builtin_amdgcn_s_barrier();
  asm volatile("" ::: "memory");
}

// ---------------------------------------------------------------------------
// Kernel P: PREP = xt_convert (blocks 0..2303) + wa_all (blocks 2304..2628).
// ---------------------------------------------------------------------------
__global__ __launch_bounds__(256)
void prep(const float* __restrict__ x, unsigned short* __restrict__ xT,
          const float* __restrict__ w, const float* __restrict__ w_off,
          unsigned short* __restrict__ Ag, unsigned short* __restrict__ Ag2,
          float* __restrict__ sumArr) {
  __shared__ unsigned short ls[64][72];
  int bx = blockIdx.x;
  int tid = threadIdx.x;

  if (bx < 2304) {
    // ---- xt_convert: bx = n*576 + cb*144 + hwt
    int n   = bx / 576;
    int rem = bx - n * 576;
    int cb  = rem / 144;
    int hwt = rem - cb * 144;
    int hwbase = hwt * 64;
    int cbase  = cb * 64;
    {
      int cl = tid >> 2, qd = tid & 3;
      const float* src = x + ((size_t)(n * CIN + cbase + cl)) * HW + hwbase + qd * 16;
#pragma unroll
      for (int m = 0; m < 4; ++m) {
        float4 v = *(const float4*)(src + m * 4);
        int hwl = qd * 16 + m * 4;
        ls[hwl + 0][cl] = f2bf(v.x);
        ls[hwl + 1][cl] = f2bf(v.y);
        ls[hwl + 2][cl] = f2bf(v.z);
        ls[hwl + 3][cl] = f2bf(v.w);
      }
    }
    __syncthreads();
    {
      int hw = tid >> 2, part = tid & 3;
      unsigned short* dst = xT + ((size_t)(n * HW + hwbase + hw)) * CIN + cbase + part * 16;
      *(uint4*)(dst + 0) = *(const uint4*)(&ls[hw][part * 16 + 0]);
      *(uint4*)(dst + 8) = *(const uint4*)(&ls[hw][part * 16 + 8]);
    }
  } else if (bx < 2592) {    // ---- main weights: 288 blocks
    int gid = (bx - 2304) * 256 + tid;
    int ch = gid >> 10;
    int rest = gid & 1023;
    int ot = rest >> 6, l = rest & 63;
    int o = ot * 16 + (l & 15);
    int k = ch >> 3, cc = ch & 7;
    int cbase = cc * 32 + (l >> 4) * 8;
    unsigned short r[8];
#pragma unroll
    for (int j = 0; j < 8; ++j)
      r[j] = f2bf(w[((size_t)o * CIN + cbase + j) * 9 + k]);
    uint4 pk;
    pk.x = (unsigned int)r[0] | ((unsigned int)r[1] << 16);
    pk.y = (unsigned int)r[2] | ((unsigned int)r[3] << 16);
    pk.z = (unsigned int)r[4] | ((unsigned int)r[5] << 16);
    pk.w = (unsigned int)r[6] | ((unsigned int)r[7] << 16);
    *(uint4*)(Ag + (size_t)gid * 8) = pk;
  } else if (bx < 2628) {    // ---- offset weights: 36 blocks
    int gid = (bx - 2592) * 256 + tid;
    int ch = gid >> 7;
    int rest = gid & 127;
    int ot = rest >> 6, l = rest & 63;
    int o = ot * 16 + (l & 15);
    int k = ch >> 3, cc = ch & 7;
    int cbase = cc * 32 + (l >> 4) * 8;
    unsigned short r[8];
#pragma unroll
    for (int j = 0; j < 8; ++j)
      r[j] = (o < 27) ? f2bf(w_off[((size_t)o * CIN + cbase + j) * 9 + k]) : (unsigned short)0;
    uint4 pk;
    pk.x = (unsigned int)r[0] | ((unsigned int)r[1] << 16);
    pk.y = (unsigned int)r[2] | ((unsigned int)r[3] << 16);
    pk.z = (unsigned int)r[4] | ((unsigned int)r[5] << 16);
    pk.w = (unsigned int)r[6] | ((unsigned int)r[7] << 16);
    *(uint4*)(Ag2 + (size_t)gid * 8) = pk;
  } else {                   // ---- zero sumArr[256] + sqArr[256] (contiguous)
    sumArr[tid] = 0.f;
    sumArr[256 + tid] = 0.f;
  }
}

// ---------------------------------------------------------------------------
// Kernel O: offset conv bf16 MFMA GEMM, BK=128 intervals, depth-2 prefetch.
// 256 threads, 64-px tiles; XCD swizzle: each XCD gets 72 contiguous tiles.
// ---------------------------------------------------------------------------
__global__ __launch_bounds__(256, 4)
void offset_gemm(const unsigned short* __restrict__ xT,
                 const unsigned short* __restrict__ Ag2,
                 const float* __restrict__ b_off,
                 float* __restrict__ py, float* __restrict__ px,
                 float* __restrict__ mk) {
  __shared__ int sPos[9][64];
  __shared__ unsigned short sB[2][2][4096];  // [bufpair][group-half][64px*64kc]

  int tid = threadIdx.x;
  int wv = tid >> 6, lane = tid & 63, quad = lane >> 4, l16 = lane & 15;
  // T1 XCD swizzle (nwg = 576, 576%8==0 -> bijective)
  int bid = blockIdx.x + 144 * blockIdx.y;
  int swz = (bid & 7) * 72 + (bid >> 3);
  int pixBase = (swz % 144) * 64;
  int n = swz / 144;
  const unsigned short* xTn = xT + (size_t)n * HW * CIN;

  if (tid < 64) {
    int hwp = pixBase + tid;
    int hh = hwp / W, wx = hwp % W;
#pragma unroll
    for (int ty = 0; ty < 3; ++ty) {
#pragma unroll
      for (int tx = 0; tx < 3; ++tx) {
        int iy = hh + ty - 1, ix = wx + tx - 1;
        bool ok = (iy >= 0) && (iy < H) && (ix >= 0) && (ix < W);
        sPos[ty * 3 + tx][tid] = ok ? (iy * W + ix) : -1;
      }
    }
  }
  bar();

  int pix0 = tid >> 3, ck0 = tid & 7;
  int pix1 = 32 + (tid >> 3);
  int a0 = (ck0 >> 2) * 2048 + (pix0 >> 4) * 512 + ((ck0 & 3) * 16 + ((pix0 & 15) ^ (ck0 & 3))) * 8;
  int a1 = (ck0 >> 2) * 2048 + (pix1 >> 4) * 512 + ((ck0 & 3) * 16 + ((pix1 & 15) ^ (ck0 & 3))) * 8;

  f32x4 acc[2];
  acc[0] = (f32x4){0.f, 0.f, 0.f, 0.f};
  acc[1] = (f32x4){0.f, 0.f, 0.f, 0.f};

  uint4 dA[2], dB[2];
  auto issue = [&](int g, uint4* d) {
    int k = g % 9, c2 = g / 9;
    int p0 = sPos[k][pix0], p1 = sPos[k][pix1];
    d[0] = (uint4){0, 0, 0, 0};
    d[1] = (uint4){0, 0, 0, 0};
    if (p0 >= 0) d[0] = *(const uint4*)(xTn + (size_t)p0 * CIN + c2 * 64 + ck0 * 8);
    if (p1 >= 0) d[1] = *(const uint4*)(xTn + (size_t)p1 * CIN + c2 * 64 + ck0 * 8);
  };

  bf16x8 afr[4];
  auto aload = [&](int g) {
    int k = g % 9, c2 = g / 9;
    int ch = k * 8 + c2 * 2;
#pragma unroll
    for (int s = 0; s < 2; ++s)
#pragma unroll
      for (int ot = 0; ot < 2; ++ot)
        afr[s * 2 + ot] = *(const bf16x8*)(Ag2 + ((size_t)((ch + s) * 2 + ot) * 64 + lane) * 8);
  };

  int rdAddr0 = wv * 512 + (quad * 16 + (l16 ^ quad)) * 8;
  auto mfmaPhase = [&](int buf, int half) {
    const unsigned short* base = &sB[buf][half][0];
#pragma unroll
    for (int s = 0; s < 2; ++s) {
      bf16x8 bfr = *(const bf16x8*)(base + s * 2048 + rdAddr0);
      acc[0] = __builtin_amdgcn_mfma_f32_16x16x32_bf16(afr[s * 2 + 0], bfr, acc[0], 0, 0, 0);
      acc[1] = __builtin_amdgcn_mfma_f32_16x16x32_bf16(afr[s * 2 + 1], bfr, acc[1], 0, 0, 0);
    }
  };
  auto store = [&](uint4* d, int buf, int half) {
    *(uint4*)(&sB[buf][half][a0]) = d[0];
    *(uint4*)(&sB[buf][half][a1]) = d[1];
  };

  // prologue: stage g0,g1 into buf0; g2,g3 corners in flight
  issue(0, dA);
  issue(1, dB);
  aload(0);
  store(dA, 0, 0);
  issue(2, dA);
  store(dB, 0, 1);
  issue(3, dB);
  bar();

  for (int i = 0; i < NIV; ++i) {
    int buf = i & 1;
    mfmaPhase(buf, 0);                   // group 2i
    aload(2 * i + 1);
    if (i < NIV - 1) store(dA, buf ^ 1, 0);      // group 2i+2
    if (i < NIV - 2) issue(2 * i + 4, dA);
    mfmaPhase(buf, 1);                   // group 2i+1
    if (i < NIV - 1) store(dB, buf ^ 1, 1);      // group 2i+3
    if (i < NIV - 2) issue(2 * i + 5, dB);
    if (i < NIV - 1) aload(2 * i + 2);
    bar();
  }

  // Epilogue
  int pix = pixBase + wv * 16 + l16;
  int he = pix / W, we = pix % W;
#pragma unroll
  for (int ot = 0; ot < 2; ++ot) {
#pragma unroll
    for (int r = 0; r < 4; ++r) {
      int kk = ot * 16 + quad * 4 + r;
      if (kk >= 27) continue;
      float v = acc[ot][r] + b_off[kk];
      if (kk < 9) {
        py[(size_t)(n * 9 + kk) * HW + pix] = v + (float)he + (float)(kk / 3 - 1);
      } else if (kk < 18) {
        int j = kk - 9;
        px[(size_t)(n * 9 + j) * HW + pix] = v + (float)we + (float)(j % 3 - 1);
      } else {
        mk[(size_t)(n * 9 + (kk - 18)) * HW + pix] = 1.f / (1.f + expf(-v));
      }
    }
  }
}

// ---------------------------------------------------------------------------
// Kernel G: FUSED bilinear-sample + bf16 MFMA GEMM, 48-px tiles, BK=128.
// Grid = 192x4 = 768 blocks = EXACTLY 3 blocks/CU (uniform CU load).
// XCD swizzle: each XCD gets 96 contiguous tiles (48 image rows ~2.4MB of
// xT incl. halo -> fits the 4MB per-XCD L2; halo re-reads become L2 hits).
// sB padded so LDS = 49664B -> HW cannot pack a 4th block on any CU.
// ---------------------------------------------------------------------------
__global__ __launch_bounds__(512, 4)
void fused_gemm(const unsigned short* __restrict__ xT,
                const unsigned short* __restrict__ Ag,
                const float* __restrict__ py,
                const float* __restrict__ px,
                const float* __restrict__ mk,
                unsigned short* __restrict__ yb,
                float* __restrict__ sumArr, float* __restrict__ sqArr) {
  __shared__ int   sIdx4[9][TPX][4];           // 6912 B
  __shared__ float sWgt4[9][TPX][4];           // 6912 B
  __shared__ unsigned short sB[2][2][4480];    // used: 3072/half; padded->3 blk/CU

  int tid = threadIdx.x;
  int wv = tid >> 6, lane = tid & 63, quad = lane >> 4, l16 = lane & 15;
  // T1 XCD swizzle (nwg = 768, 768%8==0 -> bijective)
  int bid = blockIdx.x + 192 * blockIdx.y;
  int swz = (bid & 7) * 96 + (bid >> 3);
  int pixBase = (swz % 192) * TPX;
  int n = swz / 192;
  const unsigned short* xTn = xT + (size_t)n * HW * CIN;

  // ---- prologue: corner indices + mask-folded weights, 48 px x 9 taps
  if (tid < 9 * TPX) {
    int k = tid / TPX, pix0 = tid - k * TPX;
    int off = (n * 9 + k) * HW + pixBase + pix0;
    float fy = py[off], fx = px[off], fm = mk[off];
    float y0f = floorf(fy), x0f = floorf(fx);
    float ly = fy - y0f, lx = fx - x0f;
    int y0 = (int)y0f, x0 = (int)x0f;
    int cy0 = min(max(y0, 0), H - 1), cy1 = min(max(y0 + 1, 0), H - 1);
    int cx0 = min(max(x0, 0), W - 1), cx1 = min(max(x0 + 1, 0), W - 1);
    float vy0 = (y0 >= 0 && y0 <= H - 1) ? 1.f : 0.f;
    float vy1 = (y0 + 1 >= 0 && y0 + 1 <= H - 1) ? 1.f : 0.f;
    float vx0 = (x0 >= 0 && x0 <= W - 1) ? 1.f : 0.f;
    float vx1 = (x0 + 1 >= 0 && x0 + 1 <= W - 1) ? 1.f : 0.f;
    int4 iv;
    iv.x = cy0 * W + cx0;
    iv.y = cy0 * W + cx1;
    iv.z = cy1 * W + cx0;
    iv.w = cy1 * W + cx1;
    float4 wf;
    wf.x = (1.f - ly) * (1.f - lx) * fm * vy0 * vx0;
    wf.y = (1.f - ly) * lx * fm * vy0 * vx1;
    wf.z = ly * (1.f - lx) * fm * vy1 * vx0;
    wf.w = ly * lx * fm * vy1 * vx1;
    *(int4*)(&sIdx4[k][pix0][0]) = iv;
    *(float4*)(&sWgt4[k][pix0][0]) = wf;
  }
  bar();

  // sampler role: waves 0-5; 4 consecutive lanes = 1 corner-row line
  int wvm3 = wv % 3, wvd3 = wv / 3;           // pt-tile, chunk-half (wv<6)
  bool samp = (wv < 6);
  int pixS  = (wvm3 << 4) | (lane >> 2);      // 0..47
  int qS    = lane & 3;
  int chunk = (wvd3 << 2) | qS;               // 0..7
  int co    = chunk * 8;
  int sAddr = (chunk >> 2) * 1536 + wvm3 * 512 + (qS * 16 + ((lane >> 2) ^ qS)) * 8;

  f32x4 acc[2][3];
#pragma unroll
  for (int i = 0; i < 2; ++i)
#pragma unroll
    for (int pt = 0; pt < 3; ++pt) acc[i][pt] = (f32x4){0.f, 0.f, 0.f, 0.f};

  uint4 cnA[4], cnB[4];
  float wgA[4], wgB[4];
  auto issue = [&](int g, uint4* cn, float* wt) {
    int k = g % 9, c2 = g / 9;
    int4 iv = *(const int4*)(&sIdx4[k][pixS][0]);
    float4 wf = *(const float4*)(&sWgt4[k][pixS][0]);
    int coff = c2 * 64 + co;
    cn[0] = *(const uint4*)(xTn + (size_t)iv.x * CIN + coff);
    cn[1] = *(const uint4*)(xTn + (size_t)iv.y * CIN + coff);
    cn[2] = *(const uint4*)(xTn + (size_t)iv.z * CIN + coff);
    cn[3] = *(const uint4*)(xTn + (size_t)iv.w * CIN + coff);
    wt[0] = wf.x; wt[1] = wf.y; wt[2] = wf.z; wt[3] = wf.w;
  };

  auto blendOne = [&](unsigned int u0, unsigned int u1, unsigned int u2,
                      unsigned int u3, const float* wt) -> unsigned int {
    f32x2 s = up2(u0) * wt[0];       // v_pk_fma chain
    s += up2(u1) * wt[1];
    s += up2(u2) * wt[2];
    s += up2(u3) * wt[3];
    return cvtpk(s.x, s.y);          // 1-instr RNE pack
  };
  auto blendStore = [&](uint4* cn, const float* wt, int buf, int half) {
    uint4 r;
    r.x = blendOne(cn[0].x, cn[1].x, cn[2].x, cn[3].x, wt);
    r.y = blendOne(cn[0].y, cn[1].y, cn[2].y, cn[3].y, wt);
    r.z = blendOne(cn[0].z, cn[1].z, cn[2].z, cn[3].z, wt);
    r.w = blendOne(cn[0].w, cn[1].w, cn[2].w, cn[3].w, wt);
    *(uint4*)(&sB[buf][half][sAddr]) = r;
  };

  bf16x8 afr[4];
  auto aload = [&](int g) {
    int k = g % 9, c2 = g / 9;
    int ch = k * 8 + c2 * 2;
#pragma unroll
    for (int s = 0; s < 2; ++s)
#pragma unroll
      for (int ot = 0; ot < 2; ++ot)
        afr[s * 2 + ot] = *(const bf16x8*)(Ag + ((size_t)((ch + s) * 16 + 2 * wv + ot) * 64 + lane) * 8);
  };

  int rdBase = (quad * 16 + (l16 ^ quad)) * 8;
  auto mfmaPhase = [&](int buf, int half) {
    const unsigned short* base = &sB[buf][half][0];
#pragma unroll
    for (int s = 0; s < 2; ++s) {
      bf16x8 bfr[3];
#pragma unroll
      for (int pt = 0; pt < 3; ++pt)
        bfr[pt] = *(const bf16x8*)(base + s * 1536 + pt * 512 + rdBase);
#pragma unroll
      for (int pt = 0; pt < 3; ++pt) {
        acc[0][pt] = __builtin_amdgcn_mfma_f32_16x16x32_bf16(afr[s * 2 + 0], bfr[pt], acc[0][pt], 0, 0, 0);
        acc[1][pt] = __builtin_amdgcn_mfma_f32_16x16x32_bf16(afr[s * 2 + 1], bfr[pt], acc[1][pt], 0, 0, 0);
      }
    }
  };

  // prologue: stage g0,g1 into buf0; g2,g3 corners in flight across bar
  if (samp) {
    issue(0, cnA, wgA);
    issue(1, cnB, wgB);
  }
  aload(0);
  if (samp) {
    blendStore(cnA, wgA, 0, 0);
    issue(2, cnA, wgA);
    blendStore(cnB, wgB, 0, 1);
    issue(3, cnB, wgB);
  }
  bar();

  for (int i = 0; i < NIV; ++i) {
    int buf = i & 1;
    mfmaPhase(buf, 0);                        // group 2i
    aload(2 * i + 1);
    if (samp && i < NIV - 1) blendStore(cnA, wgA, buf ^ 1, 0);   // group 2i+2
    if (samp && i < NIV - 2) issue(2 * i + 4, cnA, wgA);
    mfmaPhase(buf, 1);                        // group 2i+1
    if (samp && i < NIV - 1) blendStore(cnB, wgB, buf ^ 1, 1);   // group 2i+3
    if (samp && i < NIV - 2) issue(2 * i + 5, cnB, wgB);
    if (i < NIV - 1) aload(2 * i + 2);
    bar();
  }

  // Epilogue: D col = l16 (pix), row = quad*4 + r (o within 16-tile)
#pragma unroll
  for (int ot = 0; ot < 2; ++ot) {
#pragma unroll
    for (int r = 0; r < 4; ++r) {
      int o = (2 * wv + ot) * 16 + quad * 4 + r;
      unsigned short* rowp = yb + (size_t)(n * COUT + o) * HW + pixBase;
      float s = 0.f, q = 0.f;
#pragma unroll
      for (int pt = 0; pt < 3; ++pt) {
        float v = acc[ot][pt][r];
        rowp[pt * 16 + l16] = f2bf(v);
        s += v;
        q = fmaf(v, v, q);
      }
#pragma unroll
      for (int m = 8; m >= 1; m >>= 1) {
        s += __shfl_xor(s, m, 64);
        q += __shfl_xor(q, m, 64);
      }
      if (l16 == 0) {
        atomicAdd(&sumArr[o], s);
        atomicAdd(&sqArr[o], q);
      }
    }
  }
}

// ---------------------------------------------------------------------------
// BN apply with inlined finalize (bf16 y -> fp32 out).
// ---------------------------------------------------------------------------
__global__ __launch_bounds__(256)
void bn_apply(const unsigned short* __restrict__ yb,
              float* __restrict__ out,
              const float* __restrict__ sumArr,
              const float* __restrict__ sqArr,
              const float* __restrict__ gamma,
              const float* __restrict__ beta) {
  int gid = blockIdx.x * 256 + threadIdx.x;  // < NB*COUT*HW/8
  int base = gid * 8;
  int o = (base / HW) % COUT;
  const float inv = 1.f / (float)(NB * HW);
  float mean = sumArr[o] * inv;
  float var = sqArr[o] * inv - mean * mean;
  float scale = rsqrtf(var + 1e-5f) * gamma[o];
  float shift = beta[o] - mean * scale;
  uint4 v = ((const uint4*)yb)[gid];
  float4 a, b;
  a.x = fmaxf(fmaf(bf2f((unsigned short)(v.x & 0xffff)), scale, shift), 0.f);
  a.y = fmaxf(fmaf(bf2f((unsigned short)(v.x >> 16)), scale, shift), 0.f);
  a.z = fmaxf(fmaf(bf2f((unsigned short)(v.y & 0xffff)), scale, shift), 0.f);
  a.w = fmaxf(fmaf(bf2f((unsigned short)(v.y >> 16)), scale, shift), 0.f);
  b.x = fmaxf(fmaf(bf2f((unsigned short)(v.z & 0xffff)), scale, shift), 0.f);
  b.y = fmaxf(fmaf(bf2f((unsigned short)(v.z >> 16)), scale, shift), 0.f);
  b.z = fmaxf(fmaf(bf2f((unsigned short)(v.w & 0xffff)), scale, shift), 0.f);
  b.w = fmaxf(fmaf(bf2f((unsigned short)(v.w >> 16)), scale, shift), 0.f);
  *(float4*)&out[base] = a;
  *(float4*)&out[base + 4] = b;
}

// ---------------------------------------------------------------------------
extern "C" void kernel_launch(void* const* d_in, const int* in_sizes, int n_in,
                              void* d_out, int out_size, void* d_ws, size_t ws_size,
                              hipStream_t stream) {
  const float* x     = (const float*)d_in[0];
  const float* w_off = (const float*)d_in[1];
  const float* b_off = (const float*)d_in[2];
  const float* w     = (const float*)d_in[3];
  // d_in[4] = b : cancels exactly in BN mean-subtraction
  const float* gamma = (const float*)d_in[5];
  const float* beta  = (const float*)d_in[6];
  float* out = (float*)d_out;

  float* ws = (float*)d_ws;
  float* py = ws;                          // 331776 f
  float* px = py + 331776;
  float* mk = px + 331776;
  unsigned short* Ag  = (unsigned short*)(mk + 331776);  // 589824 u16
  unsigned short* Ag2 = Ag + 589824;                     // 73728 u16
  float* sumArr   = (float*)(Ag2 + 73728);
  float* sqArr    = sumArr + 256;                        // contiguous after sumArr
  unsigned short* yb = (unsigned short*)(sqArr + 256);   // 9437184 u16
  unsigned short* xT = yb + 9437184;                     // 9437184 u16

  prep<<<2629, 256, 0, stream>>>(x, xT, w, w_off, Ag, Ag2, sumArr);

  dim3 gO(HW / 64, NB);
  offset_gemm<<<gO, 256, 0, stream>>>(xT, Ag2, b_off, py, px, mk);

  dim3 gG(HW / TPX, NB);
  fused_gemm<<<gG, 512, 0, stream>>>(xT, Ag, py, px, mk, yb, sumArr, sqArr);

  bn_apply<<<(NB * COUT * HW / 8) / 256, 256, 0, stream>>>(yb, out, sumArr, sqArr, gamma, beta);
}